// Round 9
// baseline (239.340 us; speedup 1.0000x reference)
//
#include <hip/hip_runtime.h>

#define NB 8
#define NV 12288
#define NE 147456
#define CFM 384
#define CU 61
#define FEPS 0.005f

typedef unsigned short ushort_t;
typedef unsigned int uint_t;
typedef __attribute__((ext_vector_type(8))) unsigned short ushort8v;
typedef __attribute__((ext_vector_type(4))) unsigned short ushort4v;

__device__ inline float b2f(ushort_t u) {
    return __uint_as_float(((uint_t)u) << 16);
}
__device__ inline ushort_t f2b(float f) {   // round-nearest-even
    uint_t u = __float_as_uint(f);
    return (ushort_t)((u + 0x7fffu + ((u >> 16) & 1u)) >> 16);
}

// transpose conv_w (61,384) -> cwT (384,64), zero-pad o>=61
__global__ void k_wt(const float* __restrict__ cw, float* __restrict__ cwT) {
    int idx = blockIdx.x * 256 + threadIdx.x;
    if (idx >= CFM * 64) return;
    int c = idx >> 6, o = idx & 63;
    cwT[idx] = (o < CU) ? cw[o * CFM + c] : 0.f;
}

// pf[b][p][o] = sum_c cwT[c][o] * fm[b][c][p]
__global__ __launch_bounds__(256) void k_conv(const float* __restrict__ fm,
                                              const float* __restrict__ cwT,
                                              float* __restrict__ pf) {
    __shared__ float ftile[32][64];   // 8 KB
    int tid = threadIdx.x;
    int lane = tid & 63;
    int og = __builtin_amdgcn_readfirstlane(tid >> 6);   // wave-uniform -> SGPR
    int idx0 = blockIdx.x * 64;
    int b = idx0 >> 12, p0 = idx0 & 4095;
    const float* fb = fm + (size_t)b * CFM * 4096 + p0;
    float acc[16];
#pragma unroll
    for (int o = 0; o < 16; o++) acc[o] = 0.f;
    for (int cc = 0; cc < CFM; cc += 32) {
#pragma unroll
        for (int i = 0; i < 2; i++) {
            int lin = tid + 256 * i;
            int c = lin >> 4, pq = lin & 15;
            *(float4*)&ftile[c][pq * 4] =
                *(const float4*)(fb + (size_t)(cc + c) * 4096 + pq * 4);
        }
        __syncthreads();
#pragma unroll 8
        for (int c = 0; c < 32; c++) {
            float fv = ftile[c][lane];
            const float4* w4 = (const float4*)(cwT + (cc + c) * 64 + og * 16);
            float4 wa = w4[0], wb = w4[1], wc = w4[2], wd = w4[3];
            float w[16] = {wa.x, wa.y, wa.z, wa.w, wb.x, wb.y, wb.z, wb.w,
                           wc.x, wc.y, wc.z, wc.w, wd.x, wd.y, wd.z, wd.w};
#pragma unroll
            for (int o = 0; o < 16; o++) acc[o] = fmaf(fv, w[o], acc[o]);
        }
        __syncthreads();
    }
    float4* outp = (float4*)(pf + (size_t)(idx0 + lane) * 64 + og * 16);
#pragma unroll
    for (int o4 = 0; o4 < 4; o4++)
        outp[o4] = make_float4(acc[o4 * 4], acc[o4 * 4 + 1], acc[o4 * 4 + 2], acc[o4 * 4 + 3]);
}

// per-vertex projection + depth visibility + feature bilinear -> xfeat[v][b][64] (bf16)
__global__ void k_sample(const float* __restrict__ depth, const float* __restrict__ pf,
                         const float* __restrict__ verts, const float* __restrict__ fz,
                         const float* __restrict__ cz, const float* __restrict__ convb,
                         ushort_t* __restrict__ xfeat) {
    int t = blockIdx.x * 256 + threadIdx.x;
    int gid = t >> 4;                 // b*NV+v
    int ln = t & 15;
    int b = gid / NV;
    int v = gid - b * NV;
    const float* vp = verts + (size_t)gid * 3;
    float vx = vp[0], vy = vp[1], vz = vp[2];
    float fzb = fz[b], czb = cz[2 * b];
    float gx = fzb * vx + czb;
    float gy = fzb * vy + czb;
    float gz = fzb * (vz + 100.f);

    float px = (gx + 1.f) * 64.f - 0.5f;
    float py = (gy + 1.f) * 64.f - 0.5f;
    float fx0 = floorf(px), fy0 = floorf(py);
    float wx1 = px - fx0, wy1 = py - fy0, wx0 = 1.f - wx1, wy0 = 1.f - wy1;
    int x0 = (int)fx0, y0 = (int)fy0;
    const float* dmb = depth + (size_t)b * 128 * 128;
    float d00 = 0.f, d01 = 0.f, d10 = 0.f, d11 = 0.f;
    bool X0 = (x0 >= 0 && x0 < 128), X1 = (x0 + 1 >= 0 && x0 + 1 < 128);
    bool Y0 = (y0 >= 0 && y0 < 128), Y1 = (y0 + 1 >= 0 && y0 + 1 < 128);
    int xa = min(max(x0, 0), 127), xb = min(max(x0 + 1, 0), 127);
    int ya = min(max(y0, 0), 127), yb = min(max(y0 + 1, 0), 127);
    if (Y0 && X0) d00 = dmb[ya * 128 + xa];
    if (Y0 && X1) d01 = dmb[ya * 128 + xb];
    if (Y1 && X0) d10 = dmb[yb * 128 + xa];
    if (Y1 && X1) d11 = dmb[yb * 128 + xb];
    float sd = d00 * wy0 * wx0 + d01 * wy0 * wx1 + d10 * wy1 * wx0 + d11 * wy1 * wx1;
    float vis = (fabsf(sd - gz) < FEPS) ? 1.f : 0.f;

    float qx = (gx + 1.f) * 32.f - 0.5f;
    float qy = (gy + 1.f) * 32.f - 0.5f;
    float gx0 = floorf(qx), gy0 = floorf(qy);
    float ax1 = qx - gx0, ay1 = qy - gy0, ax0 = 1.f - ax1, ay0 = 1.f - ay1;
    int cx0 = (int)gx0, cy0 = (int)gy0;
    bool FX0 = (cx0 >= 0 && cx0 < 64), FX1 = (cx0 + 1 >= 0 && cx0 + 1 < 64);
    bool FY0 = (cy0 >= 0 && cy0 < 64), FY1 = (cy0 + 1 >= 0 && cy0 + 1 < 64);
    int fxa = min(max(cx0, 0), 63), fxb = min(max(cx0 + 1, 0), 63);
    int fya = min(max(cy0, 0), 63), fyb = min(max(cy0 + 1, 0), 63);
    float m00 = (FY0 && FX0) ? ay0 * ax0 : 0.f;
    float m01 = (FY0 && FX1) ? ay0 * ax1 : 0.f;
    float m10 = (FY1 && FX0) ? ay1 * ax0 : 0.f;
    float m11 = (FY1 && FX1) ? ay1 * ax1 : 0.f;
    const float* pfb = pf + (size_t)b * 4096 * 64;
    const float* p00 = pfb + ((size_t)fya * 64 + fxa) * 64;
    const float* p01 = pfb + ((size_t)fya * 64 + fxb) * 64;
    const float* p10 = pfb + ((size_t)fyb * 64 + fxa) * 64;
    const float* p11 = pfb + ((size_t)fyb * 64 + fxb) * 64;

    ushort_t* xr = xfeat + ((size_t)v * NB + b) * 64;
#pragma unroll
    for (int j = 0; j < 4; j++) {
        int c = ln + 16 * j;
        if (c < CU) {
            float val = m00 * p00[c] + m01 * p01[c] + m10 * p10[c] + m11 * p11[c];
            xr[c] = f2b(vis * val + convb[c]);
        } else {
            xr[c] = f2b(vp[c - CU]);
        }
    }
}

// ---- CSR build ----
__global__ void k_count(const int* __restrict__ erow, int* __restrict__ counts) {
    int e = blockIdx.x * 256 + threadIdx.x;
    if (e < NE) atomicAdd(&counts[erow[e]], 1);
}

__global__ void k_scan(const int* __restrict__ counts, int* __restrict__ offs) {
    __shared__ int part[1024];
    int t = threadIdx.x;
    int base = t * 12;
    int local[12];
    int s = 0;
#pragma unroll
    for (int i = 0; i < 12; i++) { local[i] = s; s += counts[base + i]; }
    part[t] = s;
    __syncthreads();
    for (int off = 1; off < 1024; off <<= 1) {
        int v = (t >= off) ? part[t - off] : 0;
        __syncthreads();
        part[t] += v;
        __syncthreads();
    }
    int prefix = part[t] - s;   // exclusive
#pragma unroll
    for (int i = 0; i < 12; i++) offs[base + i] = prefix + local[i];
}

__global__ void k_fill(const int* __restrict__ erow, const int* __restrict__ ecol,
                       const int* __restrict__ offs, int* __restrict__ cursor,
                       int* __restrict__ csr) {
    int e = blockIdx.x * 256 + threadIdx.x;
    if (e >= NE) return;
    int r = erow[e];
    int pos = offs[r] + atomicAdd(&cursor[r], 1);
    csr[pos] = ecol[e];
}

// gather-agg: xfeat row (512 bf16 = 1 KB) per edge; one wave per dest vertex
__global__ void k_agg1(const int* __restrict__ counts, const int* __restrict__ offs,
                       const int* __restrict__ csr, const ushort_t* __restrict__ xfeat,
                       float* __restrict__ agg1d) {
    int wid = (blockIdx.x * 256 + threadIdx.x) >> 6;   // vertex
    int l = threadIdx.x & 63;
    if (wid >= NV) return;
    int beg = offs[wid], n = counts[wid];
    float a[8];
#pragma unroll
    for (int t = 0; t < 8; t++) a[t] = 0.f;
    for (int j = 0; j < n; j++) {
        int c = csr[beg + j];
        ushort8v u = *(const ushort8v*)(xfeat + (size_t)c * 512 + l * 8);
#pragma unroll
        for (int t = 0; t < 8; t++) a[t] += b2f(u[t]);
    }
    float dinv = 1.f / fmaxf((float)n, 1.f);
    float4* dst = (float4*)(agg1d + (size_t)wid * 512 + l * 8);
    dst[0] = make_float4(a[0] * dinv, a[1] * dinv, a[2] * dinv, a[3] * dinv);
    dst[1] = make_float4(a[4] * dinv, a[5] * dinv, a[6] * dinv, a[7] * dinv);
}

// fused MLP: block = 256 = 64 rows x 4 hidden-chunk WAVES (chunk wave-uniform ->
// all weights via s_load). x in LDS [64][65]; h[32]+acc2[35] in regs.
// Cross-wave acc2 reduction via LDS atomicAdd into part[64][37] (9.5 KB).
// Total LDS ~26 KB -> 6 blocks/CU, grid 1536 = exactly 6/CU.
__global__ __launch_bounds__(256, 6) void k_mlp(
        const float* __restrict__ agg1d, const float* __restrict__ W1,
        const float* __restrict__ b1, const float* __restrict__ W2,
        const float* __restrict__ Wdv, const float* __restrict__ verts,
        ushort_t* __restrict__ y2, float* __restrict__ out) {
    __shared__ float xl[64 * 65];     // 16640 B
    __shared__ float part[64 * 37];   //  9472 B
    int tid = threadIdx.x;
    int lane = tid & 63;
    int w = __builtin_amdgcn_readfirstlane(tid >> 6);   // chunk 0..3, wave-uniform
    int base = blockIdx.x * 64;          // 1536 blocks x 64 rows

    // zero the reduction buffer (2368 floats)
    for (int i = tid; i < 64 * 37; i += 256) part[i] = 0.f;
    // stage x: thread t loads 16 consecutive floats (block reads 16 KB contiguous)
    {
        int r = tid >> 2, seg = (tid & 3) * 16;
        const float4* src = (const float4*)(agg1d + (size_t)base * 64 + tid * 16);
        float* dst = xl + r * 65 + seg;
#pragma unroll
        for (int i = 0; i < 4; i++) {
            float4 u = src[i];
            dst[4 * i + 0] = u.x; dst[4 * i + 1] = u.y;
            dst[4 * i + 2] = u.z; dst[4 * i + 3] = u.w;
        }
    }
    __syncthreads();

    // GEMM1: h[j] = relu(sum_k x[k] * W1[k][w*32+j] + b1[w*32+j])
    float h[32];
    {
        const float* bp = b1 + w * 32;
#pragma unroll
        for (int j = 0; j < 32; j++) h[j] = bp[j];
    }
    const float* xrow = xl + lane * 65;
#pragma unroll 8
    for (int k = 0; k < 64; k++) {
        float xv = xrow[k];
        const float* wk = W1 + k * 128 + w * 32;   // uniform -> s_load
#pragma unroll
        for (int j = 0; j < 32; j++) h[j] = fmaf(xv, wk[j], h[j]);
    }
#pragma unroll
    for (int j = 0; j < 32; j++) h[j] = fmaxf(h[j], 0.f);

    // GEMM2 partial: this wave's 32 hidden rows of W2/Wdv
    float acc2[35];
#pragma unroll
    for (int j = 0; j < 35; j++) acc2[j] = 0.f;
    const float* w2p = W2 + (size_t)(w * 32) * 32;
    const float* wdp = Wdv + (size_t)(w * 32) * 3;
#pragma unroll 4
    for (int kc = 0; kc < 32; kc++) {
        float hv = h[kc];
#pragma unroll
        for (int j = 0; j < 32; j++)
            acc2[j] = fmaf(hv, w2p[kc * 32 + j], acc2[j]);
        acc2[32] = fmaf(hv, wdp[kc * 3 + 0], acc2[32]);
        acc2[33] = fmaf(hv, wdp[kc * 3 + 1], acc2[33]);
        acc2[34] = fmaf(hv, wdp[kc * 3 + 2], acc2[34]);
    }
    // cross-wave reduce via LDS float atomics (ds_add_f32)
    {
        float* pp = part + lane * 37;
#pragma unroll
        for (int j = 0; j < 35; j++) atomicAdd(&pp[j], acc2[j]);
    }
    __syncthreads();

    int row = base + lane;
    if (w == 0) {          // pack y2 row: 32 bf16 = 64 B
        uint_t pk[16];
#pragma unroll
        for (int j = 0; j < 16; j++) {
            float lo = part[lane * 37 + 2 * j];
            float hi = part[lane * 37 + 2 * j + 1];
            pk[j] = (uint_t)f2b(lo) | ((uint_t)f2b(hi) << 16);
        }
        uint4* yp = (uint4*)(y2 + (size_t)row * 32);
#pragma unroll
        for (int j = 0; j < 4; j++)
            yp[j] = make_uint4(pk[4 * j], pk[4 * j + 1], pk[4 * j + 2], pk[4 * j + 3]);
    } else if (w == 1) {   // dv tail
        float e0 = part[lane * 37 + 32];
        float e1 = part[lane * 37 + 33];
        float e2 = part[lane * 37 + 34];
        int v = row >> 3, b = row & 7;
        const float* vp = verts + ((size_t)b * NV + v) * 3;
        float* orow = out + ((size_t)b * NV + v) * 38;
        orow[32] = (vp[0] + e0) * 1000.f;
        orow[33] = (vp[1] + e1) * 1000.f;
        orow[34] = (vp[2] + e2) * 1000.f;
        orow[35] = e0 * 1000.f;
        orow[36] = e1 * 1000.f;
        orow[37] = e2 * 1000.f;
    }
}

// gather-agg over y2 (256 bf16 = 512 B per vertex-row); write out[0..31]
__global__ void k_agg2(const int* __restrict__ counts, const int* __restrict__ offs,
                       const int* __restrict__ csr, const ushort_t* __restrict__ y2,
                       float* __restrict__ out) {
    int wid = (blockIdx.x * 256 + threadIdx.x) >> 6;   // vertex
    int l = threadIdx.x & 63;
    if (wid >= NV) return;
    int beg = offs[wid], n = counts[wid];
    float a[4];
#pragma unroll
    for (int t = 0; t < 4; t++) a[t] = 0.f;
    for (int j = 0; j < n; j++) {
        int c = csr[beg + j];
        ushort4v u = *(const ushort4v*)(y2 + (size_t)c * 256 + l * 4);
#pragma unroll
        for (int t = 0; t < 4; t++) a[t] += b2f(u[t]);
    }
    float dinv = 1.f / fmaxf((float)n, 1.f);
    int b = l >> 3, o = (l & 7) * 4;
    float* orow = out + ((size_t)b * NV + wid) * 38 + o;
    orow[0] = a[0] * dinv;
    orow[1] = a[1] * dinv;
    orow[2] = a[2] * dinv;
    orow[3] = a[3] * dinv;
}

extern "C" void kernel_launch(void* const* d_in, const int* in_sizes, int n_in,
                              void* d_out, int out_size, void* d_ws, size_t ws_size,
                              hipStream_t stream) {
    const float* fm  = (const float*)d_in[0];
    const float* dm  = (const float*)d_in[1];
    const float* vt  = (const float*)d_in[2];
    const float* fz  = (const float*)d_in[3];
    const float* cz  = (const float*)d_in[4];
    const float* cw  = (const float*)d_in[5];
    const float* cb  = (const float*)d_in[6];
    const float* W1  = (const float*)d_in[7];
    const float* b1  = (const float*)d_in[8];
    const float* W2  = (const float*)d_in[9];
    const float* Wdv = (const float*)d_in[10];
    const int* erow  = (const int*)d_in[11];
    const int* ecol  = (const int*)d_in[12];
    float* out = (float*)d_out;

    float* ws    = (float*)d_ws;
    float* pf    = ws;                        // 2097152 f
    float* agg1d = pf + 2097152;              // 6291456 f
    float* cwT   = agg1d + 6291456;           // 24576 f
    ushort_t* xfeat = (ushort_t*)(cwT + 24576);   // 6291456 bf16 (3145728 f)
    ushort_t* y2 = (ushort_t*)((float*)xfeat + 3145728);  // 3145728 bf16
    int* counts  = (int*)((float*)y2 + 1572864); // 12288
    int* offs    = counts + 12288;
    int* cursor  = offs + 12288;
    int* csr     = cursor + 12288;            // 147456

    hipMemsetAsync(counts, 0, 12288 * sizeof(int), stream);
    hipMemsetAsync(cursor, 0, 12288 * sizeof(int), stream);

    k_wt<<<96, 256, 0, stream>>>(cw, cwT);
    k_conv<<<512, 256, 0, stream>>>(fm, cwT, pf);
    k_sample<<<6144, 256, 0, stream>>>(dm, pf, vt, fz, cz, cb, xfeat);
    k_count<<<576, 256, 0, stream>>>(erow, counts);
    k_scan<<<1, 1024, 0, stream>>>(counts, offs);
    k_fill<<<576, 256, 0, stream>>>(erow, ecol, offs, cursor, csr);
    k_agg1<<<3072, 256, 0, stream>>>(counts, offs, csr, xfeat, agg1d);
    k_mlp<<<1536, 256, 0, stream>>>(agg1d, W1, b1, W2, Wdv, vt, y2, out);
    k_agg2<<<3072, 256, 0, stream>>>(counts, offs, csr, y2, out);
}

// Round 10
// 234.551 us; speedup vs baseline: 1.0204x; 1.0204x over previous
//
#include <hip/hip_runtime.h>

#define NB 8
#define NV 12288
#define NE 147456
#define CFM 384
#define CU 61
#define FEPS 0.005f

typedef unsigned short ushort_t;
typedef unsigned int uint_t;
typedef __attribute__((ext_vector_type(8))) unsigned short ushort8v;
typedef __attribute__((ext_vector_type(4))) unsigned short ushort4v;

__device__ inline float b2f(ushort_t u) {
    return __uint_as_float(((uint_t)u) << 16);
}
__device__ inline ushort_t f2b(float f) {   // round-nearest-even
    uint_t u = __float_as_uint(f);
    return (ushort_t)((u + 0x7fffu + ((u >> 16) & 1u)) >> 16);
}

// transpose conv_w (61,384) -> cwT (384,64), zero-pad o>=61
__global__ void k_wt(const float* __restrict__ cw, float* __restrict__ cwT) {
    int idx = blockIdx.x * 256 + threadIdx.x;
    if (idx >= CFM * 64) return;
    int c = idx >> 6, o = idx & 63;
    cwT[idx] = (o < CU) ? cw[o * CFM + c] : 0.f;
}

// pf[b][p][o] = sum_c cwT[c][o] * fm[b][c][p]
__global__ __launch_bounds__(256) void k_conv(const float* __restrict__ fm,
                                              const float* __restrict__ cwT,
                                              float* __restrict__ pf) {
    __shared__ float ftile[32][64];   // 8 KB
    int tid = threadIdx.x;
    int lane = tid & 63;
    int og = __builtin_amdgcn_readfirstlane(tid >> 6);   // wave-uniform -> SGPR
    int idx0 = blockIdx.x * 64;
    int b = idx0 >> 12, p0 = idx0 & 4095;
    const float* fb = fm + (size_t)b * CFM * 4096 + p0;
    float acc[16];
#pragma unroll
    for (int o = 0; o < 16; o++) acc[o] = 0.f;
    for (int cc = 0; cc < CFM; cc += 32) {
#pragma unroll
        for (int i = 0; i < 2; i++) {
            int lin = tid + 256 * i;
            int c = lin >> 4, pq = lin & 15;
            *(float4*)&ftile[c][pq * 4] =
                *(const float4*)(fb + (size_t)(cc + c) * 4096 + pq * 4);
        }
        __syncthreads();
#pragma unroll 8
        for (int c = 0; c < 32; c++) {
            float fv = ftile[c][lane];
            const float4* w4 = (const float4*)(cwT + (cc + c) * 64 + og * 16);
            float4 wa = w4[0], wb = w4[1], wc = w4[2], wd = w4[3];
            float w[16] = {wa.x, wa.y, wa.z, wa.w, wb.x, wb.y, wb.z, wb.w,
                           wc.x, wc.y, wc.z, wc.w, wd.x, wd.y, wd.z, wd.w};
#pragma unroll
            for (int o = 0; o < 16; o++) acc[o] = fmaf(fv, w[o], acc[o]);
        }
        __syncthreads();
    }
    float4* outp = (float4*)(pf + (size_t)(idx0 + lane) * 64 + og * 16);
#pragma unroll
    for (int o4 = 0; o4 < 4; o4++)
        outp[o4] = make_float4(acc[o4 * 4], acc[o4 * 4 + 1], acc[o4 * 4 + 2], acc[o4 * 4 + 3]);
}

// per-vertex projection + depth visibility + feature bilinear -> xfeat[v][b][64] (bf16)
__global__ void k_sample(const float* __restrict__ depth, const float* __restrict__ pf,
                         const float* __restrict__ verts, const float* __restrict__ fz,
                         const float* __restrict__ cz, const float* __restrict__ convb,
                         ushort_t* __restrict__ xfeat) {
    int t = blockIdx.x * 256 + threadIdx.x;
    int gid = t >> 4;                 // b*NV+v
    int ln = t & 15;
    int b = gid / NV;
    int v = gid - b * NV;
    const float* vp = verts + (size_t)gid * 3;
    float vx = vp[0], vy = vp[1], vz = vp[2];
    float fzb = fz[b], czb = cz[2 * b];
    float gx = fzb * vx + czb;
    float gy = fzb * vy + czb;
    float gz = fzb * (vz + 100.f);

    float px = (gx + 1.f) * 64.f - 0.5f;
    float py = (gy + 1.f) * 64.f - 0.5f;
    float fx0 = floorf(px), fy0 = floorf(py);
    float wx1 = px - fx0, wy1 = py - fy0, wx0 = 1.f - wx1, wy0 = 1.f - wy1;
    int x0 = (int)fx0, y0 = (int)fy0;
    const float* dmb = depth + (size_t)b * 128 * 128;
    float d00 = 0.f, d01 = 0.f, d10 = 0.f, d11 = 0.f;
    bool X0 = (x0 >= 0 && x0 < 128), X1 = (x0 + 1 >= 0 && x0 + 1 < 128);
    bool Y0 = (y0 >= 0 && y0 < 128), Y1 = (y0 + 1 >= 0 && y0 + 1 < 128);
    int xa = min(max(x0, 0), 127), xb = min(max(x0 + 1, 0), 127);
    int ya = min(max(y0, 0), 127), yb = min(max(y0 + 1, 0), 127);
    if (Y0 && X0) d00 = dmb[ya * 128 + xa];
    if (Y0 && X1) d01 = dmb[ya * 128 + xb];
    if (Y1 && X0) d10 = dmb[yb * 128 + xa];
    if (Y1 && X1) d11 = dmb[yb * 128 + xb];
    float sd = d00 * wy0 * wx0 + d01 * wy0 * wx1 + d10 * wy1 * wx0 + d11 * wy1 * wx1;
    float vis = (fabsf(sd - gz) < FEPS) ? 1.f : 0.f;

    float qx = (gx + 1.f) * 32.f - 0.5f;
    float qy = (gy + 1.f) * 32.f - 0.5f;
    float gx0 = floorf(qx), gy0 = floorf(qy);
    float ax1 = qx - gx0, ay1 = qy - gy0, ax0 = 1.f - ax1, ay0 = 1.f - ay1;
    int cx0 = (int)gx0, cy0 = (int)gy0;
    bool FX0 = (cx0 >= 0 && cx0 < 64), FX1 = (cx0 + 1 >= 0 && cx0 + 1 < 64);
    bool FY0 = (cy0 >= 0 && cy0 < 64), FY1 = (cy0 + 1 >= 0 && cy0 + 1 < 64);
    int fxa = min(max(cx0, 0), 63), fxb = min(max(cx0 + 1, 0), 63);
    int fya = min(max(cy0, 0), 63), fyb = min(max(cy0 + 1, 0), 63);
    float m00 = (FY0 && FX0) ? ay0 * ax0 : 0.f;
    float m01 = (FY0 && FX1) ? ay0 * ax1 : 0.f;
    float m10 = (FY1 && FX0) ? ay1 * ax0 : 0.f;
    float m11 = (FY1 && FX1) ? ay1 * ax1 : 0.f;
    const float* pfb = pf + (size_t)b * 4096 * 64;
    const float* p00 = pfb + ((size_t)fya * 64 + fxa) * 64;
    const float* p01 = pfb + ((size_t)fya * 64 + fxb) * 64;
    const float* p10 = pfb + ((size_t)fyb * 64 + fxa) * 64;
    const float* p11 = pfb + ((size_t)fyb * 64 + fxb) * 64;

    ushort_t* xr = xfeat + ((size_t)v * NB + b) * 64;
#pragma unroll
    for (int j = 0; j < 4; j++) {
        int c = ln + 16 * j;
        if (c < CU) {
            float val = m00 * p00[c] + m01 * p01[c] + m10 * p10[c] + m11 * p11[c];
            xr[c] = f2b(vis * val + convb[c]);
        } else {
            xr[c] = f2b(vp[c - CU]);
        }
    }
}

// ---- CSR build ----
__global__ void k_count(const int* __restrict__ erow, int* __restrict__ counts) {
    int e = blockIdx.x * 256 + threadIdx.x;
    if (e < NE) atomicAdd(&counts[erow[e]], 1);
}

__global__ void k_scan(const int* __restrict__ counts, int* __restrict__ offs) {
    __shared__ int part[1024];
    int t = threadIdx.x;
    int base = t * 12;
    int local[12];
    int s = 0;
#pragma unroll
    for (int i = 0; i < 12; i++) { local[i] = s; s += counts[base + i]; }
    part[t] = s;
    __syncthreads();
    for (int off = 1; off < 1024; off <<= 1) {
        int v = (t >= off) ? part[t - off] : 0;
        __syncthreads();
        part[t] += v;
        __syncthreads();
    }
    int prefix = part[t] - s;   // exclusive
#pragma unroll
    for (int i = 0; i < 12; i++) offs[base + i] = prefix + local[i];
}

__global__ void k_fill(const int* __restrict__ erow, const int* __restrict__ ecol,
                       const int* __restrict__ offs, int* __restrict__ cursor,
                       int* __restrict__ csr) {
    int e = blockIdx.x * 256 + threadIdx.x;
    if (e >= NE) return;
    int r = erow[e];
    int pos = offs[r] + atomicAdd(&cursor[r], 1);
    csr[pos] = ecol[e];
}

// gather-agg: xfeat row (512 bf16 = 1 KB) per edge; one wave per dest vertex
__global__ void k_agg1(const int* __restrict__ counts, const int* __restrict__ offs,
                       const int* __restrict__ csr, const ushort_t* __restrict__ xfeat,
                       float* __restrict__ agg1d) {
    int wid = (blockIdx.x * 256 + threadIdx.x) >> 6;   // vertex
    int l = threadIdx.x & 63;
    if (wid >= NV) return;
    int beg = offs[wid], n = counts[wid];
    float a[8];
#pragma unroll
    for (int t = 0; t < 8; t++) a[t] = 0.f;
    for (int j = 0; j < n; j++) {
        int c = csr[beg + j];
        ushort8v u = *(const ushort8v*)(xfeat + (size_t)c * 512 + l * 8);
#pragma unroll
        for (int t = 0; t < 8; t++) a[t] += b2f(u[t]);
    }
    float dinv = 1.f / fmaxf((float)n, 1.f);
    float4* dst = (float4*)(agg1d + (size_t)wid * 512 + l * 8);
    dst[0] = make_float4(a[0] * dinv, a[1] * dinv, a[2] * dinv, a[3] * dinv);
    dst[1] = make_float4(a[4] * dinv, a[5] * dinv, a[6] * dinv, a[7] * dinv);
}

// fused MLP: block = 256 = 64 rows x 4 hidden-chunk WAVES (chunk wave-uniform ->
// all weights via s_load). x in LDS [64][65]; h[32]+acc2[35] in regs.
// Cross-wave acc2 reduction via LDS atomicAdd into part[64][37] (9.5 KB).
// LDS ~26 KB. NOTE: no min-waves clause — launch_bounds(256,6) capped VGPR at
// ~85 and spilled (R9: VGPR 40, WRITE_SIZE 109 MB, 2.2x slower).
__global__ __launch_bounds__(256) void k_mlp(
        const float* __restrict__ agg1d, const float* __restrict__ W1,
        const float* __restrict__ b1, const float* __restrict__ W2,
        const float* __restrict__ Wdv, const float* __restrict__ verts,
        ushort_t* __restrict__ y2, float* __restrict__ out) {
    __shared__ float xl[64 * 65];     // 16640 B
    __shared__ float part[64 * 37];   //  9472 B
    int tid = threadIdx.x;
    int lane = tid & 63;
    int w = __builtin_amdgcn_readfirstlane(tid >> 6);   // chunk 0..3, wave-uniform
    int base = blockIdx.x * 64;          // 1536 blocks x 64 rows

    // zero the reduction buffer (2368 floats)
    for (int i = tid; i < 64 * 37; i += 256) part[i] = 0.f;
    // stage x: thread t loads 16 consecutive floats (block reads 16 KB contiguous)
    {
        int r = tid >> 2, seg = (tid & 3) * 16;
        const float4* src = (const float4*)(agg1d + (size_t)base * 64 + tid * 16);
        float* dst = xl + r * 65 + seg;
#pragma unroll
        for (int i = 0; i < 4; i++) {
            float4 u = src[i];
            dst[4 * i + 0] = u.x; dst[4 * i + 1] = u.y;
            dst[4 * i + 2] = u.z; dst[4 * i + 3] = u.w;
        }
    }
    __syncthreads();

    // GEMM1: h[j] = relu(sum_k x[k] * W1[k][w*32+j] + b1[w*32+j])
    float h[32];
    {
        const float* bp = b1 + w * 32;
#pragma unroll
        for (int j = 0; j < 32; j++) h[j] = bp[j];
    }
    const float* xrow = xl + lane * 65;
#pragma unroll 8
    for (int k = 0; k < 64; k++) {
        float xv = xrow[k];
        const float* wk = W1 + k * 128 + w * 32;   // uniform -> s_load
#pragma unroll
        for (int j = 0; j < 32; j++) h[j] = fmaf(xv, wk[j], h[j]);
    }
#pragma unroll
    for (int j = 0; j < 32; j++) h[j] = fmaxf(h[j], 0.f);

    // GEMM2 partial: this wave's 32 hidden rows of W2/Wdv
    float acc2[35];
#pragma unroll
    for (int j = 0; j < 35; j++) acc2[j] = 0.f;
    const float* w2p = W2 + (size_t)(w * 32) * 32;
    const float* wdp = Wdv + (size_t)(w * 32) * 3;
#pragma unroll 4
    for (int kc = 0; kc < 32; kc++) {
        float hv = h[kc];
#pragma unroll
        for (int j = 0; j < 32; j++)
            acc2[j] = fmaf(hv, w2p[kc * 32 + j], acc2[j]);
        acc2[32] = fmaf(hv, wdp[kc * 3 + 0], acc2[32]);
        acc2[33] = fmaf(hv, wdp[kc * 3 + 1], acc2[33]);
        acc2[34] = fmaf(hv, wdp[kc * 3 + 2], acc2[34]);
    }
    // cross-wave reduce via LDS float atomics (ds_add_f32)
    {
        float* pp = part + lane * 37;
#pragma unroll
        for (int j = 0; j < 35; j++) atomicAdd(&pp[j], acc2[j]);
    }
    __syncthreads();

    int row = base + lane;
    if (w == 0) {          // pack y2 row: 32 bf16 = 64 B
        uint_t pk[16];
#pragma unroll
        for (int j = 0; j < 16; j++) {
            float lo = part[lane * 37 + 2 * j];
            float hi = part[lane * 37 + 2 * j + 1];
            pk[j] = (uint_t)f2b(lo) | ((uint_t)f2b(hi) << 16);
        }
        uint4* yp = (uint4*)(y2 + (size_t)row * 32);
#pragma unroll
        for (int j = 0; j < 4; j++)
            yp[j] = make_uint4(pk[4 * j], pk[4 * j + 1], pk[4 * j + 2], pk[4 * j + 3]);
    } else if (w == 1) {   // dv tail
        float e0 = part[lane * 37 + 32];
        float e1 = part[lane * 37 + 33];
        float e2 = part[lane * 37 + 34];
        int v = row >> 3, b = row & 7;
        const float* vp = verts + ((size_t)b * NV + v) * 3;
        float* orow = out + ((size_t)b * NV + v) * 38;
        orow[32] = (vp[0] + e0) * 1000.f;
        orow[33] = (vp[1] + e1) * 1000.f;
        orow[34] = (vp[2] + e2) * 1000.f;
        orow[35] = e0 * 1000.f;
        orow[36] = e1 * 1000.f;
        orow[37] = e2 * 1000.f;
    }
}

// gather-agg over y2 (256 bf16 = 512 B per vertex-row); write out[0..31]
__global__ void k_agg2(const int* __restrict__ counts, const int* __restrict__ offs,
                       const int* __restrict__ csr, const ushort_t* __restrict__ y2,
                       float* __restrict__ out) {
    int wid = (blockIdx.x * 256 + threadIdx.x) >> 6;   // vertex
    int l = threadIdx.x & 63;
    if (wid >= NV) return;
    int beg = offs[wid], n = counts[wid];
    float a[4];
#pragma unroll
    for (int t = 0; t < 4; t++) a[t] = 0.f;
    for (int j = 0; j < n; j++) {
        int c = csr[beg + j];
        ushort4v u = *(const ushort4v*)(y2 + (size_t)c * 256 + l * 4);
#pragma unroll
        for (int t = 0; t < 4; t++) a[t] += b2f(u[t]);
    }
    float dinv = 1.f / fmaxf((float)n, 1.f);
    int b = l >> 3, o = (l & 7) * 4;
    float* orow = out + ((size_t)b * NV + wid) * 38 + o;
    orow[0] = a[0] * dinv;
    orow[1] = a[1] * dinv;
    orow[2] = a[2] * dinv;
    orow[3] = a[3] * dinv;
}

extern "C" void kernel_launch(void* const* d_in, const int* in_sizes, int n_in,
                              void* d_out, int out_size, void* d_ws, size_t ws_size,
                              hipStream_t stream) {
    const float* fm  = (const float*)d_in[0];
    const float* dm  = (const float*)d_in[1];
    const float* vt  = (const float*)d_in[2];
    const float* fz  = (const float*)d_in[3];
    const float* cz  = (const float*)d_in[4];
    const float* cw  = (const float*)d_in[5];
    const float* cb  = (const float*)d_in[6];
    const float* W1  = (const float*)d_in[7];
    const float* b1  = (const float*)d_in[8];
    const float* W2  = (const float*)d_in[9];
    const float* Wdv = (const float*)d_in[10];
    const int* erow  = (const int*)d_in[11];
    const int* ecol  = (const int*)d_in[12];
    float* out = (float*)d_out;

    float* ws    = (float*)d_ws;
    float* pf    = ws;                        // 2097152 f
    float* agg1d = pf + 2097152;              // 6291456 f
    float* cwT   = agg1d + 6291456;           // 24576 f
    ushort_t* xfeat = (ushort_t*)(cwT + 24576);   // 6291456 bf16 (3145728 f)
    ushort_t* y2 = (ushort_t*)((float*)xfeat + 3145728);  // 3145728 bf16
    int* counts  = (int*)((float*)y2 + 1572864); // 12288
    int* offs    = counts + 12288;
    int* cursor  = offs + 12288;
    int* csr     = cursor + 12288;            // 147456

    hipMemsetAsync(counts, 0, 12288 * sizeof(int), stream);
    hipMemsetAsync(cursor, 0, 12288 * sizeof(int), stream);

    k_wt<<<96, 256, 0, stream>>>(cw, cwT);
    k_conv<<<512, 256, 0, stream>>>(fm, cwT, pf);
    k_sample<<<6144, 256, 0, stream>>>(dm, pf, vt, fz, cz, cb, xfeat);
    k_count<<<576, 256, 0, stream>>>(erow, counts);
    k_scan<<<1, 1024, 0, stream>>>(counts, offs);
    k_fill<<<576, 256, 0, stream>>>(erow, ecol, offs, cursor, csr);
    k_agg1<<<3072, 256, 0, stream>>>(counts, offs, csr, xfeat, agg1d);
    k_mlp<<<1536, 256, 0, stream>>>(agg1d, W1, b1, W2, Wdv, vt, y2, out);
    k_agg2<<<3072, 256, 0, stream>>>(counts, offs, csr, y2, out);
}

// Round 11
// 173.015 us; speedup vs baseline: 1.3833x; 1.3557x over previous
//
#include <hip/hip_runtime.h>

#define NB 8
#define NV 12288
#define NE 147456
#define CFM 384
#define CU 61
#define FEPS 0.005f

typedef unsigned short ushort_t;
typedef unsigned int uint_t;
typedef __attribute__((ext_vector_type(8))) unsigned short ushort8v;
typedef __attribute__((ext_vector_type(4))) unsigned short ushort4v;

__device__ inline float b2f(ushort_t u) {
    return __uint_as_float(((uint_t)u) << 16);
}
__device__ inline ushort_t f2b(float f) {   // round-nearest-even
    uint_t u = __float_as_uint(f);
    return (ushort_t)((u + 0x7fffu + ((u >> 16) & 1u)) >> 16);
}

// transpose conv_w (61,384) -> cwT (384,64), zero-pad o>=61
__global__ void k_wt(const float* __restrict__ cw, float* __restrict__ cwT) {
    int idx = blockIdx.x * 256 + threadIdx.x;
    if (idx >= CFM * 64) return;
    int c = idx >> 6, o = idx & 63;
    cwT[idx] = (o < CU) ? cw[o * CFM + c] : 0.f;
}

// pf[b][p][o] = sum_c cwT[c][o] * fm[b][c][p]
__global__ __launch_bounds__(256) void k_conv(const float* __restrict__ fm,
                                              const float* __restrict__ cwT,
                                              float* __restrict__ pf) {
    __shared__ float ftile[32][64];   // 8 KB
    int tid = threadIdx.x;
    int lane = tid & 63;
    int og = __builtin_amdgcn_readfirstlane(tid >> 6);   // wave-uniform -> SGPR
    int idx0 = blockIdx.x * 64;
    int b = idx0 >> 12, p0 = idx0 & 4095;
    const float* fb = fm + (size_t)b * CFM * 4096 + p0;
    float acc[16];
#pragma unroll
    for (int o = 0; o < 16; o++) acc[o] = 0.f;
    for (int cc = 0; cc < CFM; cc += 32) {
#pragma unroll
        for (int i = 0; i < 2; i++) {
            int lin = tid + 256 * i;
            int c = lin >> 4, pq = lin & 15;
            *(float4*)&ftile[c][pq * 4] =
                *(const float4*)(fb + (size_t)(cc + c) * 4096 + pq * 4);
        }
        __syncthreads();
#pragma unroll 8
        for (int c = 0; c < 32; c++) {
            float fv = ftile[c][lane];
            const float4* w4 = (const float4*)(cwT + (cc + c) * 64 + og * 16);
            float4 wa = w4[0], wb = w4[1], wc = w4[2], wd = w4[3];
            float w[16] = {wa.x, wa.y, wa.z, wa.w, wb.x, wb.y, wb.z, wb.w,
                           wc.x, wc.y, wc.z, wc.w, wd.x, wd.y, wd.z, wd.w};
#pragma unroll
            for (int o = 0; o < 16; o++) acc[o] = fmaf(fv, w[o], acc[o]);
        }
        __syncthreads();
    }
    float4* outp = (float4*)(pf + (size_t)(idx0 + lane) * 64 + og * 16);
#pragma unroll
    for (int o4 = 0; o4 < 4; o4++)
        outp[o4] = make_float4(acc[o4 * 4], acc[o4 * 4 + 1], acc[o4 * 4 + 2], acc[o4 * 4 + 3]);
}

// per-vertex projection + depth visibility + feature bilinear -> xfeat[v][b][64] (bf16)
__global__ void k_sample(const float* __restrict__ depth, const float* __restrict__ pf,
                         const float* __restrict__ verts, const float* __restrict__ fz,
                         const float* __restrict__ cz, const float* __restrict__ convb,
                         ushort_t* __restrict__ xfeat) {
    int t = blockIdx.x * 256 + threadIdx.x;
    int gid = t >> 4;                 // b*NV+v
    int ln = t & 15;
    int b = gid / NV;
    int v = gid - b * NV;
    const float* vp = verts + (size_t)gid * 3;
    float vx = vp[0], vy = vp[1], vz = vp[2];
    float fzb = fz[b], czb = cz[2 * b];
    float gx = fzb * vx + czb;
    float gy = fzb * vy + czb;
    float gz = fzb * (vz + 100.f);

    float px = (gx + 1.f) * 64.f - 0.5f;
    float py = (gy + 1.f) * 64.f - 0.5f;
    float fx0 = floorf(px), fy0 = floorf(py);
    float wx1 = px - fx0, wy1 = py - fy0, wx0 = 1.f - wx1, wy0 = 1.f - wy1;
    int x0 = (int)fx0, y0 = (int)fy0;
    const float* dmb = depth + (size_t)b * 128 * 128;
    float d00 = 0.f, d01 = 0.f, d10 = 0.f, d11 = 0.f;
    bool X0 = (x0 >= 0 && x0 < 128), X1 = (x0 + 1 >= 0 && x0 + 1 < 128);
    bool Y0 = (y0 >= 0 && y0 < 128), Y1 = (y0 + 1 >= 0 && y0 + 1 < 128);
    int xa = min(max(x0, 0), 127), xb = min(max(x0 + 1, 0), 127);
    int ya = min(max(y0, 0), 127), yb = min(max(y0 + 1, 0), 127);
    if (Y0 && X0) d00 = dmb[ya * 128 + xa];
    if (Y0 && X1) d01 = dmb[ya * 128 + xb];
    if (Y1 && X0) d10 = dmb[yb * 128 + xa];
    if (Y1 && X1) d11 = dmb[yb * 128 + xb];
    float sd = d00 * wy0 * wx0 + d01 * wy0 * wx1 + d10 * wy1 * wx0 + d11 * wy1 * wx1;
    float vis = (fabsf(sd - gz) < FEPS) ? 1.f : 0.f;

    float qx = (gx + 1.f) * 32.f - 0.5f;
    float qy = (gy + 1.f) * 32.f - 0.5f;
    float gx0 = floorf(qx), gy0 = floorf(qy);
    float ax1 = qx - gx0, ay1 = qy - gy0, ax0 = 1.f - ax1, ay0 = 1.f - ay1;
    int cx0 = (int)gx0, cy0 = (int)gy0;
    bool FX0 = (cx0 >= 0 && cx0 < 64), FX1 = (cx0 + 1 >= 0 && cx0 + 1 < 64);
    bool FY0 = (cy0 >= 0 && cy0 < 64), FY1 = (cy0 + 1 >= 0 && cy0 + 1 < 64);
    int fxa = min(max(cx0, 0), 63), fxb = min(max(cx0 + 1, 0), 63);
    int fya = min(max(cy0, 0), 63), fyb = min(max(cy0 + 1, 0), 63);
    float m00 = (FY0 && FX0) ? ay0 * ax0 : 0.f;
    float m01 = (FY0 && FX1) ? ay0 * ax1 : 0.f;
    float m10 = (FY1 && FX0) ? ay1 * ax0 : 0.f;
    float m11 = (FY1 && FX1) ? ay1 * ax1 : 0.f;
    const float* pfb = pf + (size_t)b * 4096 * 64;
    const float* p00 = pfb + ((size_t)fya * 64 + fxa) * 64;
    const float* p01 = pfb + ((size_t)fya * 64 + fxb) * 64;
    const float* p10 = pfb + ((size_t)fyb * 64 + fxa) * 64;
    const float* p11 = pfb + ((size_t)fyb * 64 + fxb) * 64;

    ushort_t* xr = xfeat + ((size_t)v * NB + b) * 64;
#pragma unroll
    for (int j = 0; j < 4; j++) {
        int c = ln + 16 * j;
        if (c < CU) {
            float val = m00 * p00[c] + m01 * p01[c] + m10 * p10[c] + m11 * p11[c];
            xr[c] = f2b(vis * val + convb[c]);
        } else {
            xr[c] = f2b(vp[c - CU]);
        }
    }
}

// ---- CSR build ----
__global__ void k_count(const int* __restrict__ erow, int* __restrict__ counts) {
    int e = blockIdx.x * 256 + threadIdx.x;
    if (e < NE) atomicAdd(&counts[erow[e]], 1);
}

__global__ void k_scan(const int* __restrict__ counts, int* __restrict__ offs) {
    __shared__ int part[1024];
    int t = threadIdx.x;
    int base = t * 12;
    int local[12];
    int s = 0;
#pragma unroll
    for (int i = 0; i < 12; i++) { local[i] = s; s += counts[base + i]; }
    part[t] = s;
    __syncthreads();
    for (int off = 1; off < 1024; off <<= 1) {
        int v = (t >= off) ? part[t - off] : 0;
        __syncthreads();
        part[t] += v;
        __syncthreads();
    }
    int prefix = part[t] - s;   // exclusive
#pragma unroll
    for (int i = 0; i < 12; i++) offs[base + i] = prefix + local[i];
}

__global__ void k_fill(const int* __restrict__ erow, const int* __restrict__ ecol,
                       const int* __restrict__ offs, int* __restrict__ cursor,
                       int* __restrict__ csr) {
    int e = blockIdx.x * 256 + threadIdx.x;
    if (e >= NE) return;
    int r = erow[e];
    int pos = offs[r] + atomicAdd(&cursor[r], 1);
    csr[pos] = ecol[e];
}

// gather-agg: xfeat row (512 bf16 = 1 KB) per edge; one wave per dest vertex
__global__ void k_agg1(const int* __restrict__ counts, const int* __restrict__ offs,
                       const int* __restrict__ csr, const ushort_t* __restrict__ xfeat,
                       float* __restrict__ agg1d) {
    int wid = (blockIdx.x * 256 + threadIdx.x) >> 6;   // vertex
    int l = threadIdx.x & 63;
    if (wid >= NV) return;
    int beg = offs[wid], n = counts[wid];
    float a[8];
#pragma unroll
    for (int t = 0; t < 8; t++) a[t] = 0.f;
    for (int j = 0; j < n; j++) {
        int c = csr[beg + j];
        ushort8v u = *(const ushort8v*)(xfeat + (size_t)c * 512 + l * 8);
#pragma unroll
        for (int t = 0; t < 8; t++) a[t] += b2f(u[t]);
    }
    float dinv = 1.f / fmaxf((float)n, 1.f);
    float4* dst = (float4*)(agg1d + (size_t)wid * 512 + l * 8);
    dst[0] = make_float4(a[0] * dinv, a[1] * dinv, a[2] * dinv, a[3] * dinv);
    dst[1] = make_float4(a[4] * dinv, a[5] * dinv, a[6] * dinv, a[7] * dinv);
}

// fused MLP: block = 256 = 64 rows x 4 hidden-chunk WAVES (chunk wave-uniform ->
// all weights via s_load). R8 compute structure (store+tree-reduce, VGPR 68,
// no spill) with xl/part TIME-SHARED in one union buffer:
//   phase 1: smem = xl[64][65] (x staging, read by GEMM1)
//   phase 2: smem = part[4][64][37] (cross-wave acc2 reduce)
// LDS = 37888 B -> 4 blocks/CU (vs R8's 54.8KB/2). R10's LDS-atomicAdd variant
// perturbed regalloc to VGPR=40 + scratch spill — do NOT use atomics here.
__global__ __launch_bounds__(256) void k_mlp(
        const float* __restrict__ agg1d, const float* __restrict__ W1,
        const float* __restrict__ b1, const float* __restrict__ W2,
        const float* __restrict__ Wdv, const float* __restrict__ verts,
        ushort_t* __restrict__ y2, float* __restrict__ out) {
    __shared__ float smem[4 * 64 * 37];   // 37888 B; xl (4160 f) aliases front
    float* xl = smem;                     // [64][65], phase 1
    float* part = smem;                   // [4][64][37], phase 2
    int tid = threadIdx.x;
    int lane = tid & 63;
    int w = __builtin_amdgcn_readfirstlane(tid >> 6);   // chunk 0..3, wave-uniform
    int base = blockIdx.x * 64;          // 1536 blocks x 64 rows

    // stage x: thread t loads 16 consecutive floats (block reads 16 KB contiguous)
    {
        int r = tid >> 2, seg = (tid & 3) * 16;
        const float4* src = (const float4*)(agg1d + (size_t)base * 64 + tid * 16);
        float* dst = xl + r * 65 + seg;
#pragma unroll
        for (int i = 0; i < 4; i++) {
            float4 u = src[i];
            dst[4 * i + 0] = u.x; dst[4 * i + 1] = u.y;
            dst[4 * i + 2] = u.z; dst[4 * i + 3] = u.w;
        }
    }
    __syncthreads();

    // GEMM1: h[j] = relu(sum_k x[k] * W1[k][w*32+j] + b1[w*32+j])
    float h[32];
    {
        const float* bp = b1 + w * 32;
#pragma unroll
        for (int j = 0; j < 32; j++) h[j] = bp[j];
    }
    const float* xrow = xl + lane * 65;
#pragma unroll 8
    for (int k = 0; k < 64; k++) {
        float xv = xrow[k];
        const float* wk = W1 + k * 128 + w * 32;   // uniform -> s_load
#pragma unroll
        for (int j = 0; j < 32; j++) h[j] = fmaf(xv, wk[j], h[j]);
    }
#pragma unroll
    for (int j = 0; j < 32; j++) h[j] = fmaxf(h[j], 0.f);

    // GEMM2 partial: this wave's 32 hidden rows of W2/Wdv
    float acc2[35];
#pragma unroll
    for (int j = 0; j < 35; j++) acc2[j] = 0.f;
    const float* w2p = W2 + (size_t)(w * 32) * 32;
    const float* wdp = Wdv + (size_t)(w * 32) * 3;
#pragma unroll 4
    for (int kc = 0; kc < 32; kc++) {
        float hv = h[kc];
#pragma unroll
        for (int j = 0; j < 32; j++)
            acc2[j] = fmaf(hv, w2p[kc * 32 + j], acc2[j]);
        acc2[32] = fmaf(hv, wdp[kc * 3 + 0], acc2[32]);
        acc2[33] = fmaf(hv, wdp[kc * 3 + 1], acc2[33]);
        acc2[34] = fmaf(hv, wdp[kc * 3 + 2], acc2[34]);
    }
    __syncthreads();   // xl reads done -> smem becomes part
    {
        float* pp = part + ((size_t)w * 64 + lane) * 37;
#pragma unroll
        for (int j = 0; j < 35; j++) pp[j] = acc2[j];
    }
    __syncthreads();

    // reduce: thread (r=lane, g=w) owns j in [g*9, min(g*9+9,35))
    {
        int j0 = w * 9, j1 = (w == 3) ? 35 : (w * 9 + 9);
        for (int j = j0; j < j1; j++) {
            float s = part[(0 * 64 + lane) * 37 + j] + part[(1 * 64 + lane) * 37 + j]
                    + part[(2 * 64 + lane) * 37 + j] + part[(3 * 64 + lane) * 37 + j];
            part[(0 * 64 + lane) * 37 + j] = s;
        }
    }
    __syncthreads();

    int row = base + lane;
    if (w == 0) {          // pack y2 row: 32 bf16 = 64 B
        uint_t pk[16];
#pragma unroll
        for (int j = 0; j < 16; j++) {
            float lo = part[lane * 37 + 2 * j];
            float hi = part[lane * 37 + 2 * j + 1];
            pk[j] = (uint_t)f2b(lo) | ((uint_t)f2b(hi) << 16);
        }
        uint4* yp = (uint4*)(y2 + (size_t)row * 32);
#pragma unroll
        for (int j = 0; j < 4; j++)
            yp[j] = make_uint4(pk[4 * j], pk[4 * j + 1], pk[4 * j + 2], pk[4 * j + 3]);
    } else if (w == 1) {   // dv tail
        float e0 = part[lane * 37 + 32];
        float e1 = part[lane * 37 + 33];
        float e2 = part[lane * 37 + 34];
        int v = row >> 3, b = row & 7;
        const float* vp = verts + ((size_t)b * NV + v) * 3;
        float* orow = out + ((size_t)b * NV + v) * 38;
        orow[32] = (vp[0] + e0) * 1000.f;
        orow[33] = (vp[1] + e1) * 1000.f;
        orow[34] = (vp[2] + e2) * 1000.f;
        orow[35] = e0 * 1000.f;
        orow[36] = e1 * 1000.f;
        orow[37] = e2 * 1000.f;
    }
}

// gather-agg over y2 (256 bf16 = 512 B per vertex-row); write out[0..31]
__global__ void k_agg2(const int* __restrict__ counts, const int* __restrict__ offs,
                       const int* __restrict__ csr, const ushort_t* __restrict__ y2,
                       float* __restrict__ out) {
    int wid = (blockIdx.x * 256 + threadIdx.x) >> 6;   // vertex
    int l = threadIdx.x & 63;
    if (wid >= NV) return;
    int beg = offs[wid], n = counts[wid];
    float a[4];
#pragma unroll
    for (int t = 0; t < 4; t++) a[t] = 0.f;
    for (int j = 0; j < n; j++) {
        int c = csr[beg + j];
        ushort4v u = *(const ushort4v*)(y2 + (size_t)c * 256 + l * 4);
#pragma unroll
        for (int t = 0; t < 4; t++) a[t] += b2f(u[t]);
    }
    float dinv = 1.f / fmaxf((float)n, 1.f);
    int b = l >> 3, o = (l & 7) * 4;
    float* orow = out + ((size_t)b * NV + wid) * 38 + o;
    orow[0] = a[0] * dinv;
    orow[1] = a[1] * dinv;
    orow[2] = a[2] * dinv;
    orow[3] = a[3] * dinv;
}

extern "C" void kernel_launch(void* const* d_in, const int* in_sizes, int n_in,
                              void* d_out, int out_size, void* d_ws, size_t ws_size,
                              hipStream_t stream) {
    const float* fm  = (const float*)d_in[0];
    const float* dm  = (const float*)d_in[1];
    const float* vt  = (const float*)d_in[2];
    const float* fz  = (const float*)d_in[3];
    const float* cz  = (const float*)d_in[4];
    const float* cw  = (const float*)d_in[5];
    const float* cb  = (const float*)d_in[6];
    const float* W1  = (const float*)d_in[7];
    const float* b1  = (const float*)d_in[8];
    const float* W2  = (const float*)d_in[9];
    const float* Wdv = (const float*)d_in[10];
    const int* erow  = (const int*)d_in[11];
    const int* ecol  = (const int*)d_in[12];
    float* out = (float*)d_out;

    float* ws    = (float*)d_ws;
    float* pf    = ws;                        // 2097152 f
    float* agg1d = pf + 2097152;              // 6291456 f
    float* cwT   = agg1d + 6291456;           // 24576 f
    ushort_t* xfeat = (ushort_t*)(cwT + 24576);   // 6291456 bf16 (3145728 f)
    ushort_t* y2 = (ushort_t*)((float*)xfeat + 3145728);  // 3145728 bf16
    int* counts  = (int*)((float*)y2 + 1572864); // 12288
    int* offs    = counts + 12288;
    int* cursor  = offs + 12288;
    int* csr     = cursor + 12288;            // 147456

    hipMemsetAsync(counts, 0, 12288 * sizeof(int), stream);
    hipMemsetAsync(cursor, 0, 12288 * sizeof(int), stream);

    k_wt<<<96, 256, 0, stream>>>(cw, cwT);
    k_conv<<<512, 256, 0, stream>>>(fm, cwT, pf);
    k_sample<<<6144, 256, 0, stream>>>(dm, pf, vt, fz, cz, cb, xfeat);
    k_count<<<576, 256, 0, stream>>>(erow, counts);
    k_scan<<<1, 1024, 0, stream>>>(counts, offs);
    k_fill<<<576, 256, 0, stream>>>(erow, ecol, offs, cursor, csr);
    k_agg1<<<3072, 256, 0, stream>>>(counts, offs, csr, xfeat, agg1d);
    k_mlp<<<1536, 256, 0, stream>>>(agg1d, W1, b1, W2, Wdv, vt, y2, out);
    k_agg2<<<3072, 256, 0, stream>>>(counts, offs, csr, y2, out);
}

// Round 12
// 170.317 us; speedup vs baseline: 1.4053x; 1.0158x over previous
//
#include <hip/hip_runtime.h>

#define NB 8
#define NV 12288
#define NE 147456
#define CFM 384
#define CU 61
#define FEPS 0.005f

typedef unsigned short ushort_t;
typedef unsigned int uint_t;
typedef __attribute__((ext_vector_type(8))) unsigned short ushort8v;
typedef __attribute__((ext_vector_type(4))) unsigned short ushort4v;

__device__ inline float b2f(ushort_t u) {
    return __uint_as_float(((uint_t)u) << 16);
}
__device__ inline ushort_t f2b(float f) {   // round-nearest-even
    uint_t u = __float_as_uint(f);
    return (ushort_t)((u + 0x7fffu + ((u >> 16) & 1u)) >> 16);
}

// transpose conv_w (61,384) -> cwT (384,64), zero-pad o>=61
__global__ void k_wt(const float* __restrict__ cw, float* __restrict__ cwT) {
    int idx = blockIdx.x * 256 + threadIdx.x;
    if (idx >= CFM * 64) return;
    int c = idx >> 6, o = idx & 63;
    cwT[idx] = (o < CU) ? cw[o * CFM + c] : 0.f;
}

// pf[b][p][o] = sum_c cwT[c][o] * fm[b][c][p]  (pf stored bf16)
__global__ __launch_bounds__(256) void k_conv(const float* __restrict__ fm,
                                              const float* __restrict__ cwT,
                                              ushort_t* __restrict__ pf) {
    __shared__ float ftile[32][64];   // 8 KB
    int tid = threadIdx.x;
    int lane = tid & 63;
    int og = __builtin_amdgcn_readfirstlane(tid >> 6);   // wave-uniform -> SGPR
    int idx0 = blockIdx.x * 64;
    int b = idx0 >> 12, p0 = idx0 & 4095;
    const float* fb = fm + (size_t)b * CFM * 4096 + p0;
    float acc[16];
#pragma unroll
    for (int o = 0; o < 16; o++) acc[o] = 0.f;
    for (int cc = 0; cc < CFM; cc += 32) {
#pragma unroll
        for (int i = 0; i < 2; i++) {
            int lin = tid + 256 * i;
            int c = lin >> 4, pq = lin & 15;
            *(float4*)&ftile[c][pq * 4] =
                *(const float4*)(fb + (size_t)(cc + c) * 4096 + pq * 4);
        }
        __syncthreads();
#pragma unroll 8
        for (int c = 0; c < 32; c++) {
            float fv = ftile[c][lane];
            const float4* w4 = (const float4*)(cwT + (cc + c) * 64 + og * 16);
            float4 wa = w4[0], wb = w4[1], wc = w4[2], wd = w4[3];
            float w[16] = {wa.x, wa.y, wa.z, wa.w, wb.x, wb.y, wb.z, wb.w,
                           wc.x, wc.y, wc.z, wc.w, wd.x, wd.y, wd.z, wd.w};
#pragma unroll
            for (int o = 0; o < 16; o++) acc[o] = fmaf(fv, w[o], acc[o]);
        }
        __syncthreads();
    }
    // pack 16 bf16 (32 B) per thread
    uint_t pk[8];
#pragma unroll
    for (int j = 0; j < 8; j++)
        pk[j] = (uint_t)f2b(acc[2 * j]) | ((uint_t)f2b(acc[2 * j + 1]) << 16);
    uint4* outp = (uint4*)(pf + (size_t)(idx0 + lane) * 64 + og * 16);
    outp[0] = make_uint4(pk[0], pk[1], pk[2], pk[3]);
    outp[1] = make_uint4(pk[4], pk[5], pk[6], pk[7]);
}

// per-vertex projection + depth visibility + feature bilinear -> xfeat[v][b][64] (bf16)
__global__ void k_sample(const float* __restrict__ depth, const ushort_t* __restrict__ pf,
                         const float* __restrict__ verts, const float* __restrict__ fz,
                         const float* __restrict__ cz, const float* __restrict__ convb,
                         ushort_t* __restrict__ xfeat) {
    int t = blockIdx.x * 256 + threadIdx.x;
    int gid = t >> 4;                 // b*NV+v
    int ln = t & 15;
    int b = gid / NV;
    int v = gid - b * NV;
    const float* vp = verts + (size_t)gid * 3;
    float vx = vp[0], vy = vp[1], vz = vp[2];
    float fzb = fz[b], czb = cz[2 * b];
    float gx = fzb * vx + czb;
    float gy = fzb * vy + czb;
    float gz = fzb * (vz + 100.f);

    float px = (gx + 1.f) * 64.f - 0.5f;
    float py = (gy + 1.f) * 64.f - 0.5f;
    float fx0 = floorf(px), fy0 = floorf(py);
    float wx1 = px - fx0, wy1 = py - fy0, wx0 = 1.f - wx1, wy0 = 1.f - wy1;
    int x0 = (int)fx0, y0 = (int)fy0;
    const float* dmb = depth + (size_t)b * 128 * 128;
    float d00 = 0.f, d01 = 0.f, d10 = 0.f, d11 = 0.f;
    bool X0 = (x0 >= 0 && x0 < 128), X1 = (x0 + 1 >= 0 && x0 + 1 < 128);
    bool Y0 = (y0 >= 0 && y0 < 128), Y1 = (y0 + 1 >= 0 && y0 + 1 < 128);
    int xa = min(max(x0, 0), 127), xb = min(max(x0 + 1, 0), 127);
    int ya = min(max(y0, 0), 127), yb = min(max(y0 + 1, 0), 127);
    if (Y0 && X0) d00 = dmb[ya * 128 + xa];
    if (Y0 && X1) d01 = dmb[ya * 128 + xb];
    if (Y1 && X0) d10 = dmb[yb * 128 + xa];
    if (Y1 && X1) d11 = dmb[yb * 128 + xb];
    float sd = d00 * wy0 * wx0 + d01 * wy0 * wx1 + d10 * wy1 * wx0 + d11 * wy1 * wx1;
    float vis = (fabsf(sd - gz) < FEPS) ? 1.f : 0.f;

    float qx = (gx + 1.f) * 32.f - 0.5f;
    float qy = (gy + 1.f) * 32.f - 0.5f;
    float gx0 = floorf(qx), gy0 = floorf(qy);
    float ax1 = qx - gx0, ay1 = qy - gy0, ax0 = 1.f - ax1, ay0 = 1.f - ay1;
    int cx0 = (int)gx0, cy0 = (int)gy0;
    bool FX0 = (cx0 >= 0 && cx0 < 64), FX1 = (cx0 + 1 >= 0 && cx0 + 1 < 64);
    bool FY0 = (cy0 >= 0 && cy0 < 64), FY1 = (cy0 + 1 >= 0 && cy0 + 1 < 64);
    int fxa = min(max(cx0, 0), 63), fxb = min(max(cx0 + 1, 0), 63);
    int fya = min(max(cy0, 0), 63), fyb = min(max(cy0 + 1, 0), 63);
    float m00 = (FY0 && FX0) ? ay0 * ax0 : 0.f;
    float m01 = (FY0 && FX1) ? ay0 * ax1 : 0.f;
    float m10 = (FY1 && FX0) ? ay1 * ax0 : 0.f;
    float m11 = (FY1 && FX1) ? ay1 * ax1 : 0.f;
    const ushort_t* pfb = pf + (size_t)b * 4096 * 64;
    const ushort_t* p00 = pfb + ((size_t)fya * 64 + fxa) * 64;
    const ushort_t* p01 = pfb + ((size_t)fya * 64 + fxb) * 64;
    const ushort_t* p10 = pfb + ((size_t)fyb * 64 + fxa) * 64;
    const ushort_t* p11 = pfb + ((size_t)fyb * 64 + fxb) * 64;

    ushort_t* xr = xfeat + ((size_t)v * NB + b) * 64;
#pragma unroll
    for (int j = 0; j < 4; j++) {
        int c = ln + 16 * j;
        if (c < CU) {
            float val = m00 * b2f(p00[c]) + m01 * b2f(p01[c])
                      + m10 * b2f(p10[c]) + m11 * b2f(p11[c]);
            xr[c] = f2b(vis * val + convb[c]);
        } else {
            xr[c] = f2b(vp[c - CU]);
        }
    }
}

// ---- CSR build ----
__global__ void k_count(const int* __restrict__ erow, int* __restrict__ counts) {
    int e = blockIdx.x * 256 + threadIdx.x;
    if (e < NE) atomicAdd(&counts[erow[e]], 1);
}

__global__ void k_scan(const int* __restrict__ counts, int* __restrict__ offs) {
    __shared__ int part[1024];
    int t = threadIdx.x;
    int base = t * 12;
    int local[12];
    int s = 0;
#pragma unroll
    for (int i = 0; i < 12; i++) { local[i] = s; s += counts[base + i]; }
    part[t] = s;
    __syncthreads();
    for (int off = 1; off < 1024; off <<= 1) {
        int v = (t >= off) ? part[t - off] : 0;
        __syncthreads();
        part[t] += v;
        __syncthreads();
    }
    int prefix = part[t] - s;   // exclusive
#pragma unroll
    for (int i = 0; i < 12; i++) offs[base + i] = prefix + local[i];
}

__global__ void k_fill(const int* __restrict__ erow, const int* __restrict__ ecol,
                       const int* __restrict__ offs, int* __restrict__ cursor,
                       int* __restrict__ csr) {
    int e = blockIdx.x * 256 + threadIdx.x;
    if (e >= NE) return;
    int r = erow[e];
    int pos = offs[r] + atomicAdd(&cursor[r], 1);
    csr[pos] = ecol[e];
}

// gather-agg: xfeat row (512 bf16 = 1 KB) per edge; one wave per dest vertex
__global__ void k_agg1(const int* __restrict__ counts, const int* __restrict__ offs,
                       const int* __restrict__ csr, const ushort_t* __restrict__ xfeat,
                       float* __restrict__ agg1d) {
    int wid = (blockIdx.x * 256 + threadIdx.x) >> 6;   // vertex
    int l = threadIdx.x & 63;
    if (wid >= NV) return;
    int beg = offs[wid], n = counts[wid];
    float a[8];
#pragma unroll
    for (int t = 0; t < 8; t++) a[t] = 0.f;
    for (int j = 0; j < n; j++) {
        int c = csr[beg + j];
        ushort8v u = *(const ushort8v*)(xfeat + (size_t)c * 512 + l * 8);
#pragma unroll
        for (int t = 0; t < 8; t++) a[t] += b2f(u[t]);
    }
    float dinv = 1.f / fmaxf((float)n, 1.f);
    float4* dst = (float4*)(agg1d + (size_t)wid * 512 + l * 8);
    dst[0] = make_float4(a[0] * dinv, a[1] * dinv, a[2] * dinv, a[3] * dinv);
    dst[1] = make_float4(a[4] * dinv, a[5] * dinv, a[6] * dinv, a[7] * dinv);
}

// fused MLP: block = 256 = 64 rows x 4 hidden-chunk WAVES (chunk wave-uniform ->
// all weights via s_load). R11 structure with a 2-PHASE cross-wave reduction:
//   smem union = max(xl[64][65]=16640B, part2[2][64][37]=18944B) = 18944 B
//   -> 8 blocks/CU LDS capacity (was 4 at 37.9KB).
//   waves 2,3 write -> waves 0,1 accumulate -> wave 1 writes -> wave 0 finishes
//   IN REGISTERS (y2 pack + dv tail straight from acc2, no final LDS trip).
__global__ __launch_bounds__(256) void k_mlp(
        const float* __restrict__ agg1d, const float* __restrict__ W1,
        const float* __restrict__ b1, const float* __restrict__ W2,
        const float* __restrict__ Wdv, const float* __restrict__ verts,
        ushort_t* __restrict__ y2, float* __restrict__ out) {
    __shared__ float smem[2 * 64 * 37];   // 18944 B; xl (4160 f) aliases front
    float* xl = smem;                     // [64][65], phase 1
    float* part2 = smem;                  // [2][64][37], phase 2
    int tid = threadIdx.x;
    int lane = tid & 63;
    int w = __builtin_amdgcn_readfirstlane(tid >> 6);   // chunk 0..3, wave-uniform
    int base = blockIdx.x * 64;          // 1536 blocks x 64 rows

    // stage x: thread t loads 16 consecutive floats (block reads 16 KB contiguous)
    {
        int r = tid >> 2, seg = (tid & 3) * 16;
        const float4* src = (const float4*)(agg1d + (size_t)base * 64 + tid * 16);
        float* dst = xl + r * 65 + seg;
#pragma unroll
        for (int i = 0; i < 4; i++) {
            float4 u = src[i];
            dst[4 * i + 0] = u.x; dst[4 * i + 1] = u.y;
            dst[4 * i + 2] = u.z; dst[4 * i + 3] = u.w;
        }
    }
    __syncthreads();

    // GEMM1: h[j] = relu(sum_k x[k] * W1[k][w*32+j] + b1[w*32+j])
    float h[32];
    {
        const float* bp = b1 + w * 32;
#pragma unroll
        for (int j = 0; j < 32; j++) h[j] = bp[j];
    }
    const float* xrow = xl + lane * 65;
#pragma unroll 8
    for (int k = 0; k < 64; k++) {
        float xv = xrow[k];
        const float* wk = W1 + k * 128 + w * 32;   // uniform -> s_load
#pragma unroll
        for (int j = 0; j < 32; j++) h[j] = fmaf(xv, wk[j], h[j]);
    }
#pragma unroll
    for (int j = 0; j < 32; j++) h[j] = fmaxf(h[j], 0.f);

    // GEMM2 partial: this wave's 32 hidden rows of W2/Wdv
    float acc2[35];
#pragma unroll
    for (int j = 0; j < 35; j++) acc2[j] = 0.f;
    const float* w2p = W2 + (size_t)(w * 32) * 32;
    const float* wdp = Wdv + (size_t)(w * 32) * 3;
#pragma unroll 4
    for (int kc = 0; kc < 32; kc++) {
        float hv = h[kc];
#pragma unroll
        for (int j = 0; j < 32; j++)
            acc2[j] = fmaf(hv, w2p[kc * 32 + j], acc2[j]);
        acc2[32] = fmaf(hv, wdp[kc * 3 + 0], acc2[32]);
        acc2[33] = fmaf(hv, wdp[kc * 3 + 1], acc2[33]);
        acc2[34] = fmaf(hv, wdp[kc * 3 + 2], acc2[34]);
    }
    __syncthreads();   // xl reads done -> smem becomes part2

    // phase A: waves 2,3 publish
    if (w >= 2) {
        float* pp = part2 + ((size_t)(w - 2) * 64 + lane) * 37;
#pragma unroll
        for (int j = 0; j < 35; j++) pp[j] = acc2[j];
    }
    __syncthreads();
    // phase B: waves 0,1 accumulate their partner
    if (w < 2) {
        const float* pp = part2 + ((size_t)w * 64 + lane) * 37;
#pragma unroll
        for (int j = 0; j < 35; j++) acc2[j] += pp[j];
    }
    __syncthreads();   // WAR: wave 0's reads of part2[0] done before wave 1 overwrites
    // phase C: wave 1 publishes
    if (w == 1) {
        float* pp = part2 + (size_t)lane * 37;
#pragma unroll
        for (int j = 0; j < 35; j++) pp[j] = acc2[j];
    }
    __syncthreads();
    // phase D: wave 0 finishes in registers
    if (w == 0) {
        const float* pp = part2 + (size_t)lane * 37;
#pragma unroll
        for (int j = 0; j < 35; j++) acc2[j] += pp[j];
        int row = base + lane;
        uint_t pk[16];
#pragma unroll
        for (int j = 0; j < 16; j++)
            pk[j] = (uint_t)f2b(acc2[2 * j]) | ((uint_t)f2b(acc2[2 * j + 1]) << 16);
        uint4* yp = (uint4*)(y2 + (size_t)row * 32);
#pragma unroll
        for (int j = 0; j < 4; j++)
            yp[j] = make_uint4(pk[4 * j], pk[4 * j + 1], pk[4 * j + 2], pk[4 * j + 3]);
        float e0 = acc2[32], e1 = acc2[33], e2 = acc2[34];
        int v = row >> 3, b = row & 7;
        const float* vp = verts + ((size_t)b * NV + v) * 3;
        float* orow = out + ((size_t)b * NV + v) * 38;
        orow[32] = (vp[0] + e0) * 1000.f;
        orow[33] = (vp[1] + e1) * 1000.f;
        orow[34] = (vp[2] + e2) * 1000.f;
        orow[35] = e0 * 1000.f;
        orow[36] = e1 * 1000.f;
        orow[37] = e2 * 1000.f;
    }
}

// gather-agg over y2 (256 bf16 = 512 B per vertex-row); write out[0..31]
__global__ void k_agg2(const int* __restrict__ counts, const int* __restrict__ offs,
                       const int* __restrict__ csr, const ushort_t* __restrict__ y2,
                       float* __restrict__ out) {
    int wid = (blockIdx.x * 256 + threadIdx.x) >> 6;   // vertex
    int l = threadIdx.x & 63;
    if (wid >= NV) return;
    int beg = offs[wid], n = counts[wid];
    float a[4];
#pragma unroll
    for (int t = 0; t < 4; t++) a[t] = 0.f;
    for (int j = 0; j < n; j++) {
        int c = csr[beg + j];
        ushort4v u = *(const ushort4v*)(y2 + (size_t)c * 256 + l * 4);
#pragma unroll
        for (int t = 0; t < 4; t++) a[t] += b2f(u[t]);
    }
    float dinv = 1.f / fmaxf((float)n, 1.f);
    int b = l >> 3, o = (l & 7) * 4;
    float* orow = out + ((size_t)b * NV + wid) * 38 + o;
    orow[0] = a[0] * dinv;
    orow[1] = a[1] * dinv;
    orow[2] = a[2] * dinv;
    orow[3] = a[3] * dinv;
}

extern "C" void kernel_launch(void* const* d_in, const int* in_sizes, int n_in,
                              void* d_out, int out_size, void* d_ws, size_t ws_size,
                              hipStream_t stream) {
    const float* fm  = (const float*)d_in[0];
    const float* dm  = (const float*)d_in[1];
    const float* vt  = (const float*)d_in[2];
    const float* fz  = (const float*)d_in[3];
    const float* cz  = (const float*)d_in[4];
    const float* cw  = (const float*)d_in[5];
    const float* cb  = (const float*)d_in[6];
    const float* W1  = (const float*)d_in[7];
    const float* b1  = (const float*)d_in[8];
    const float* W2  = (const float*)d_in[9];
    const float* Wdv = (const float*)d_in[10];
    const int* erow  = (const int*)d_in[11];
    const int* ecol  = (const int*)d_in[12];
    float* out = (float*)d_out;

    float* ws    = (float*)d_ws;
    float* agg1d = ws;                            // 6291456 f
    float* cwT   = agg1d + 6291456;               // 24576 f
    ushort_t* pf = (ushort_t*)(cwT + 24576);      // 2097152 bf16 (1048576 f)
    ushort_t* xfeat = (ushort_t*)((float*)pf + 1048576);   // 6291456 bf16
    ushort_t* y2 = (ushort_t*)((float*)xfeat + 3145728);   // 3145728 bf16
    int* counts  = (int*)((float*)y2 + 1572864);  // 12288
    int* offs    = counts + 12288;
    int* cursor  = offs + 12288;
    int* csr     = cursor + 12288;                // 147456

    hipMemsetAsync(counts, 0, 12288 * sizeof(int), stream);
    hipMemsetAsync(cursor, 0, 12288 * sizeof(int), stream);

    k_wt<<<96, 256, 0, stream>>>(cw, cwT);
    k_conv<<<512, 256, 0, stream>>>(fm, cwT, pf);
    k_sample<<<6144, 256, 0, stream>>>(dm, pf, vt, fz, cz, cb, xfeat);
    k_count<<<576, 256, 0, stream>>>(erow, counts);
    k_scan<<<1, 1024, 0, stream>>>(counts, offs);
    k_fill<<<576, 256, 0, stream>>>(erow, ecol, offs, cursor, csr);
    k_agg1<<<3072, 256, 0, stream>>>(counts, offs, csr, xfeat, agg1d);
    k_mlp<<<1536, 256, 0, stream>>>(agg1d, W1, b1, W2, Wdv, vt, y2, out);
    k_agg2<<<3072, 256, 0, stream>>>(counts, offs, csr, y2, out);
}

// Round 13
// 168.537 us; speedup vs baseline: 1.4201x; 1.0106x over previous
//
#include <hip/hip_runtime.h>

#define NB 8
#define NV 12288
#define NE 147456
#define CFM 384
#define CU 61
#define FEPS 0.005f

typedef unsigned short ushort_t;
typedef unsigned int uint_t;
typedef __attribute__((ext_vector_type(8))) unsigned short ushort8v;
typedef __attribute__((ext_vector_type(4))) unsigned short ushort4v;

__device__ inline float b2f(ushort_t u) {
    return __uint_as_float(((uint_t)u) << 16);
}
__device__ inline ushort_t f2b(float f) {   // round-nearest-even
    uint_t u = __float_as_uint(f);
    return (ushort_t)((u + 0x7fffu + ((u >> 16) & 1u)) >> 16);
}

// transpose conv_w (61,384) -> cwT (384,64), zero-pad o>=61
__global__ void k_wt(const float* __restrict__ cw, float* __restrict__ cwT) {
    int idx = blockIdx.x * 256 + threadIdx.x;
    if (idx >= CFM * 64) return;
    int c = idx >> 6, o = idx & 63;
    cwT[idx] = (o < CU) ? cw[o * CFM + c] : 0.f;
}

// pf[b][p][o] = sum_c cwT[c][o] * fm[b][c][p]  (pf stored bf16)
// block = 512 threads = 64 positions x 8 og-waves of 8 outputs (og wave-uniform
// -> s_load weights). 512 blocks x 8 waves = 4 waves/SIMD (R12 was 2: 43 us,
// VALUBusy 23%, issue/latency-bound).
__global__ __launch_bounds__(512) void k_conv(const float* __restrict__ fm,
                                              const float* __restrict__ cwT,
                                              ushort_t* __restrict__ pf) {
    __shared__ float ftile[32][64];   // 8 KB
    int tid = threadIdx.x;
    int lane = tid & 63;
    int og = __builtin_amdgcn_readfirstlane(tid >> 6);   // 0..7, wave-uniform
    int idx0 = blockIdx.x * 64;
    int b = idx0 >> 12, p0 = idx0 & 4095;
    const float* fb = fm + (size_t)b * CFM * 4096 + p0;
    float acc[8];
#pragma unroll
    for (int o = 0; o < 8; o++) acc[o] = 0.f;
    for (int cc = 0; cc < CFM; cc += 32) {
        // stage 32x64 fm tile: 512 float4, exactly 1 per thread, coalesced
        {
            int c = tid >> 4, pq = tid & 15;
            *(float4*)&ftile[c][pq * 4] =
                *(const float4*)(fb + (size_t)(cc + c) * 4096 + pq * 4);
        }
        __syncthreads();
#pragma unroll 8
        for (int c = 0; c < 32; c++) {
            float fv = ftile[c][lane];
            const float4* w4 = (const float4*)(cwT + (cc + c) * 64 + og * 8);
            float4 wa = w4[0], wb = w4[1];
            float w[8] = {wa.x, wa.y, wa.z, wa.w, wb.x, wb.y, wb.z, wb.w};
#pragma unroll
            for (int o = 0; o < 8; o++) acc[o] = fmaf(fv, w[o], acc[o]);
        }
        __syncthreads();
    }
    // pack 8 bf16 (16 B) per thread
    uint_t pk[4];
#pragma unroll
    for (int j = 0; j < 4; j++)
        pk[j] = (uint_t)f2b(acc[2 * j]) | ((uint_t)f2b(acc[2 * j + 1]) << 16);
    uint4* outp = (uint4*)(pf + (size_t)(idx0 + lane) * 64 + og * 8);
    outp[0] = make_uint4(pk[0], pk[1], pk[2], pk[3]);
}

// per-vertex projection + depth visibility + feature bilinear -> xfeat[v][b][64] (bf16)
__global__ void k_sample(const float* __restrict__ depth, const ushort_t* __restrict__ pf,
                         const float* __restrict__ verts, const float* __restrict__ fz,
                         const float* __restrict__ cz, const float* __restrict__ convb,
                         ushort_t* __restrict__ xfeat) {
    int t = blockIdx.x * 256 + threadIdx.x;
    int gid = t >> 4;                 // b*NV+v
    int ln = t & 15;
    int b = gid / NV;
    int v = gid - b * NV;
    const float* vp = verts + (size_t)gid * 3;
    float vx = vp[0], vy = vp[1], vz = vp[2];
    float fzb = fz[b], czb = cz[2 * b];
    float gx = fzb * vx + czb;
    float gy = fzb * vy + czb;
    float gz = fzb * (vz + 100.f);

    float px = (gx + 1.f) * 64.f - 0.5f;
    float py = (gy + 1.f) * 64.f - 0.5f;
    float fx0 = floorf(px), fy0 = floorf(py);
    float wx1 = px - fx0, wy1 = py - fy0, wx0 = 1.f - wx1, wy0 = 1.f - wy1;
    int x0 = (int)fx0, y0 = (int)fy0;
    const float* dmb = depth + (size_t)b * 128 * 128;
    float d00 = 0.f, d01 = 0.f, d10 = 0.f, d11 = 0.f;
    bool X0 = (x0 >= 0 && x0 < 128), X1 = (x0 + 1 >= 0 && x0 + 1 < 128);
    bool Y0 = (y0 >= 0 && y0 < 128), Y1 = (y0 + 1 >= 0 && y0 + 1 < 128);
    int xa = min(max(x0, 0), 127), xb = min(max(x0 + 1, 0), 127);
    int ya = min(max(y0, 0), 127), yb = min(max(y0 + 1, 0), 127);
    if (Y0 && X0) d00 = dmb[ya * 128 + xa];
    if (Y0 && X1) d01 = dmb[ya * 128 + xb];
    if (Y1 && X0) d10 = dmb[yb * 128 + xa];
    if (Y1 && X1) d11 = dmb[yb * 128 + xb];
    float sd = d00 * wy0 * wx0 + d01 * wy0 * wx1 + d10 * wy1 * wx0 + d11 * wy1 * wx1;
    float vis = (fabsf(sd - gz) < FEPS) ? 1.f : 0.f;

    float qx = (gx + 1.f) * 32.f - 0.5f;
    float qy = (gy + 1.f) * 32.f - 0.5f;
    float gx0 = floorf(qx), gy0 = floorf(qy);
    float ax1 = qx - gx0, ay1 = qy - gy0, ax0 = 1.f - ax1, ay0 = 1.f - ay1;
    int cx0 = (int)gx0, cy0 = (int)gy0;
    bool FX0 = (cx0 >= 0 && cx0 < 64), FX1 = (cx0 + 1 >= 0 && cx0 + 1 < 64);
    bool FY0 = (cy0 >= 0 && cy0 < 64), FY1 = (cy0 + 1 >= 0 && cy0 + 1 < 64);
    int fxa = min(max(cx0, 0), 63), fxb = min(max(cx0 + 1, 0), 63);
    int fya = min(max(cy0, 0), 63), fyb = min(max(cy0 + 1, 0), 63);
    float m00 = (FY0 && FX0) ? ay0 * ax0 : 0.f;
    float m01 = (FY0 && FX1) ? ay0 * ax1 : 0.f;
    float m10 = (FY1 && FX0) ? ay1 * ax0 : 0.f;
    float m11 = (FY1 && FX1) ? ay1 * ax1 : 0.f;
    const ushort_t* pfb = pf + (size_t)b * 4096 * 64;
    const ushort_t* p00 = pfb + ((size_t)fya * 64 + fxa) * 64;
    const ushort_t* p01 = pfb + ((size_t)fya * 64 + fxb) * 64;
    const ushort_t* p10 = pfb + ((size_t)fyb * 64 + fxa) * 64;
    const ushort_t* p11 = pfb + ((size_t)fyb * 64 + fxb) * 64;

    ushort_t* xr = xfeat + ((size_t)v * NB + b) * 64;
#pragma unroll
    for (int j = 0; j < 4; j++) {
        int c = ln + 16 * j;
        if (c < CU) {
            float val = m00 * b2f(p00[c]) + m01 * b2f(p01[c])
                      + m10 * b2f(p10[c]) + m11 * b2f(p11[c]);
            xr[c] = f2b(vis * val + convb[c]);
        } else {
            xr[c] = f2b(vp[c - CU]);
        }
    }
}

// ---- CSR build ----
__global__ void k_count(const int* __restrict__ erow, int* __restrict__ counts) {
    int e = blockIdx.x * 256 + threadIdx.x;
    if (e < NE) atomicAdd(&counts[erow[e]], 1);
}

__global__ void k_scan(const int* __restrict__ counts, int* __restrict__ offs) {
    __shared__ int part[1024];
    int t = threadIdx.x;
    int base = t * 12;
    int local[12];
    int s = 0;
#pragma unroll
    for (int i = 0; i < 12; i++) { local[i] = s; s += counts[base + i]; }
    part[t] = s;
    __syncthreads();
    for (int off = 1; off < 1024; off <<= 1) {
        int v = (t >= off) ? part[t - off] : 0;
        __syncthreads();
        part[t] += v;
        __syncthreads();
    }
    int prefix = part[t] - s;   // exclusive
#pragma unroll
    for (int i = 0; i < 12; i++) offs[base + i] = prefix + local[i];
}

__global__ void k_fill(const int* __restrict__ erow, const int* __restrict__ ecol,
                       const int* __restrict__ offs, int* __restrict__ cursor,
                       int* __restrict__ csr) {
    int e = blockIdx.x * 256 + threadIdx.x;
    if (e >= NE) return;
    int r = erow[e];
    int pos = offs[r] + atomicAdd(&cursor[r], 1);
    csr[pos] = ecol[e];
}

// gather-agg: xfeat row (512 bf16 = 1 KB) per edge; one wave per dest vertex
__global__ void k_agg1(const int* __restrict__ counts, const int* __restrict__ offs,
                       const int* __restrict__ csr, const ushort_t* __restrict__ xfeat,
                       float* __restrict__ agg1d) {
    int wid = (blockIdx.x * 256 + threadIdx.x) >> 6;   // vertex
    int l = threadIdx.x & 63;
    if (wid >= NV) return;
    int beg = offs[wid], n = counts[wid];
    float a[8];
#pragma unroll
    for (int t = 0; t < 8; t++) a[t] = 0.f;
    for (int j = 0; j < n; j++) {
        int c = csr[beg + j];
        ushort8v u = *(const ushort8v*)(xfeat + (size_t)c * 512 + l * 8);
#pragma unroll
        for (int t = 0; t < 8; t++) a[t] += b2f(u[t]);
    }
    float dinv = 1.f / fmaxf((float)n, 1.f);
    float4* dst = (float4*)(agg1d + (size_t)wid * 512 + l * 8);
    dst[0] = make_float4(a[0] * dinv, a[1] * dinv, a[2] * dinv, a[3] * dinv);
    dst[1] = make_float4(a[4] * dinv, a[5] * dinv, a[6] * dinv, a[7] * dinv);
}

// fused MLP: block = 256 = 64 rows x 4 hidden-chunk WAVES (chunk wave-uniform ->
// all weights via s_load). 2-phase cross-wave reduction; smem union 18944 B.
__global__ __launch_bounds__(256) void k_mlp(
        const float* __restrict__ agg1d, const float* __restrict__ W1,
        const float* __restrict__ b1, const float* __restrict__ W2,
        const float* __restrict__ Wdv, const float* __restrict__ verts,
        ushort_t* __restrict__ y2, float* __restrict__ out) {
    __shared__ float smem[2 * 64 * 37];   // 18944 B; xl (4160 f) aliases front
    float* xl = smem;                     // [64][65], phase 1
    float* part2 = smem;                  // [2][64][37], phase 2
    int tid = threadIdx.x;
    int lane = tid & 63;
    int w = __builtin_amdgcn_readfirstlane(tid >> 6);   // chunk 0..3, wave-uniform
    int base = blockIdx.x * 64;          // 1536 blocks x 64 rows

    // stage x: thread t loads 16 consecutive floats (block reads 16 KB contiguous)
    {
        int r = tid >> 2, seg = (tid & 3) * 16;
        const float4* src = (const float4*)(agg1d + (size_t)base * 64 + tid * 16);
        float* dst = xl + r * 65 + seg;
#pragma unroll
        for (int i = 0; i < 4; i++) {
            float4 u = src[i];
            dst[4 * i + 0] = u.x; dst[4 * i + 1] = u.y;
            dst[4 * i + 2] = u.z; dst[4 * i + 3] = u.w;
        }
    }
    __syncthreads();

    // GEMM1: h[j] = relu(sum_k x[k] * W1[k][w*32+j] + b1[w*32+j])
    float h[32];
    {
        const float* bp = b1 + w * 32;
#pragma unroll
        for (int j = 0; j < 32; j++) h[j] = bp[j];
    }
    const float* xrow = xl + lane * 65;
#pragma unroll 8
    for (int k = 0; k < 64; k++) {
        float xv = xrow[k];
        const float* wk = W1 + k * 128 + w * 32;   // uniform -> s_load
#pragma unroll
        for (int j = 0; j < 32; j++) h[j] = fmaf(xv, wk[j], h[j]);
    }
#pragma unroll
    for (int j = 0; j < 32; j++) h[j] = fmaxf(h[j], 0.f);

    // GEMM2 partial: this wave's 32 hidden rows of W2/Wdv
    float acc2[35];
#pragma unroll
    for (int j = 0; j < 35; j++) acc2[j] = 0.f;
    const float* w2p = W2 + (size_t)(w * 32) * 32;
    const float* wdp = Wdv + (size_t)(w * 32) * 3;
#pragma unroll 4
    for (int kc = 0; kc < 32; kc++) {
        float hv = h[kc];
#pragma unroll
        for (int j = 0; j < 32; j++)
            acc2[j] = fmaf(hv, w2p[kc * 32 + j], acc2[j]);
        acc2[32] = fmaf(hv, wdp[kc * 3 + 0], acc2[32]);
        acc2[33] = fmaf(hv, wdp[kc * 3 + 1], acc2[33]);
        acc2[34] = fmaf(hv, wdp[kc * 3 + 2], acc2[34]);
    }
    __syncthreads();   // xl reads done -> smem becomes part2

    // phase A: waves 2,3 publish
    if (w >= 2) {
        float* pp = part2 + ((size_t)(w - 2) * 64 + lane) * 37;
#pragma unroll
        for (int j = 0; j < 35; j++) pp[j] = acc2[j];
    }
    __syncthreads();
    // phase B: waves 0,1 accumulate their partner
    if (w < 2) {
        const float* pp = part2 + ((size_t)w * 64 + lane) * 37;
#pragma unroll
        for (int j = 0; j < 35; j++) acc2[j] += pp[j];
    }
    __syncthreads();   // WAR: wave 0's reads of part2[0] done before wave 1 overwrites
    // phase C: wave 1 publishes
    if (w == 1) {
        float* pp = part2 + (size_t)lane * 37;
#pragma unroll
        for (int j = 0; j < 35; j++) pp[j] = acc2[j];
    }
    __syncthreads();
    // phase D: wave 0 finishes in registers
    if (w == 0) {
        const float* pp = part2 + (size_t)lane * 37;
#pragma unroll
        for (int j = 0; j < 35; j++) acc2[j] += pp[j];
        int row = base + lane;
        uint_t pk[16];
#pragma unroll
        for (int j = 0; j < 16; j++)
            pk[j] = (uint_t)f2b(acc2[2 * j]) | ((uint_t)f2b(acc2[2 * j + 1]) << 16);
        uint4* yp = (uint4*)(y2 + (size_t)row * 32);
#pragma unroll
        for (int j = 0; j < 4; j++)
            yp[j] = make_uint4(pk[4 * j], pk[4 * j + 1], pk[4 * j + 2], pk[4 * j + 3]);
        float e0 = acc2[32], e1 = acc2[33], e2 = acc2[34];
        int v = row >> 3, b = row & 7;
        const float* vp = verts + ((size_t)b * NV + v) * 3;
        float* orow = out + ((size_t)b * NV + v) * 38;
        orow[32] = (vp[0] + e0) * 1000.f;
        orow[33] = (vp[1] + e1) * 1000.f;
        orow[34] = (vp[2] + e2) * 1000.f;
        orow[35] = e0 * 1000.f;
        orow[36] = e1 * 1000.f;
        orow[37] = e2 * 1000.f;
    }
}

// gather-agg over y2 (256 bf16 = 512 B per vertex-row); write out[0..31]
__global__ void k_agg2(const int* __restrict__ counts, const int* __restrict__ offs,
                       const int* __restrict__ csr, const ushort_t* __restrict__ y2,
                       float* __restrict__ out) {
    int wid = (blockIdx.x * 256 + threadIdx.x) >> 6;   // vertex
    int l = threadIdx.x & 63;
    if (wid >= NV) return;
    int beg = offs[wid], n = counts[wid];
    float a[4];
#pragma unroll
    for (int t = 0; t < 4; t++) a[t] = 0.f;
    for (int j = 0; j < n; j++) {
        int c = csr[beg + j];
        ushort4v u = *(const ushort4v*)(y2 + (size_t)c * 256 + l * 4);
#pragma unroll
        for (int t = 0; t < 4; t++) a[t] += b2f(u[t]);
    }
    float dinv = 1.f / fmaxf((float)n, 1.f);
    int b = l >> 3, o = (l & 7) * 4;
    float* orow = out + ((size_t)b * NV + wid) * 38 + o;
    orow[0] = a[0] * dinv;
    orow[1] = a[1] * dinv;
    orow[2] = a[2] * dinv;
    orow[3] = a[3] * dinv;
}

extern "C" void kernel_launch(void* const* d_in, const int* in_sizes, int n_in,
                              void* d_out, int out_size, void* d_ws, size_t ws_size,
                              hipStream_t stream) {
    const float* fm  = (const float*)d_in[0];
    const float* dm  = (const float*)d_in[1];
    const float* vt  = (const float*)d_in[2];
    const float* fz  = (const float*)d_in[3];
    const float* cz  = (const float*)d_in[4];
    const float* cw  = (const float*)d_in[5];
    const float* cb  = (const float*)d_in[6];
    const float* W1  = (const float*)d_in[7];
    const float* b1  = (const float*)d_in[8];
    const float* W2  = (const float*)d_in[9];
    const float* Wdv = (const float*)d_in[10];
    const int* erow  = (const int*)d_in[11];
    const int* ecol  = (const int*)d_in[12];
    float* out = (float*)d_out;

    float* ws    = (float*)d_ws;
    float* agg1d = ws;                            // 6291456 f
    float* cwT   = agg1d + 6291456;               // 24576 f
    ushort_t* pf = (ushort_t*)(cwT + 24576);      // 2097152 bf16 (1048576 f)
    ushort_t* xfeat = (ushort_t*)((float*)pf + 1048576);   // 6291456 bf16
    ushort_t* y2 = (ushort_t*)((float*)xfeat + 3145728);   // 3145728 bf16
    int* counts  = (int*)((float*)y2 + 1572864);  // 12288
    int* offs    = counts + 12288;
    int* cursor  = offs + 12288;
    int* csr     = cursor + 12288;                // 147456

    hipMemsetAsync(counts, 0, 12288 * sizeof(int), stream);
    hipMemsetAsync(cursor, 0, 12288 * sizeof(int), stream);

    k_wt<<<96, 256, 0, stream>>>(cw, cwT);
    k_conv<<<512, 512, 0, stream>>>(fm, cwT, pf);
    k_sample<<<6144, 256, 0, stream>>>(dm, pf, vt, fz, cz, cb, xfeat);
    k_count<<<576, 256, 0, stream>>>(erow, counts);
    k_scan<<<1, 1024, 0, stream>>>(counts, offs);
    k_fill<<<576, 256, 0, stream>>>(erow, ecol, offs, cursor, csr);
    k_agg1<<<3072, 256, 0, stream>>>(counts, offs, csr, xfeat, agg1d);
    k_mlp<<<1536, 256, 0, stream>>>(agg1d, W1, b1, W2, Wdv, vt, y2, out);
    k_agg2<<<3072, 256, 0, stream>>>(counts, offs, csr, y2, out);
}

// Round 14
// 162.773 us; speedup vs baseline: 1.4704x; 1.0354x over previous
//
#include <hip/hip_runtime.h>

#define NB 8
#define NV 12288
#define NE 147456
#define CFM 384
#define CU 61
#define FEPS 0.005f

typedef unsigned short ushort_t;
typedef unsigned int uint_t;
typedef __attribute__((ext_vector_type(8))) unsigned short ushort8v;
typedef __attribute__((ext_vector_type(4))) unsigned short ushort4v;

__device__ inline float b2f(ushort_t u) {
    return __uint_as_float(((uint_t)u) << 16);
}
__device__ inline ushort_t f2b(float f) {   // round-nearest-even
    uint_t u = __float_as_uint(f);
    return (ushort_t)((u + 0x7fffu + ((u >> 16) & 1u)) >> 16);
}

// transpose conv_w (61,384) -> cwT (384,64), zero-pad o>=61
__global__ void k_wt(const float* __restrict__ cw, float* __restrict__ cwT) {
    int idx = blockIdx.x * 256 + threadIdx.x;
    if (idx >= CFM * 64) return;
    int c = idx >> 6, o = idx & 63;
    cwT[idx] = (o < CU) ? cw[o * CFM + c] : 0.f;
}

// pf[b][p][o] = sum_c cwT[c][o] * fm[b][c][p]  (pf stored bf16)
// block = 512 = 64 positions x 8 og-waves of 8 outputs (og wave-uniform -> s_load).
// T14 async-STAGE: chunk cc+1's global load issues into REGISTERS right after
// the tile-ready barrier; vmcnt waits only at the next ds_write. R13's version
// serialized the ~900cy HBM latency with compute inside every chunk (43 us,
// 700 GB/s effective, VALUBusy 26%).
__global__ __launch_bounds__(512) void k_conv(const float* __restrict__ fm,
                                              const float* __restrict__ cwT,
                                              ushort_t* __restrict__ pf) {
    __shared__ float ftile[32][64];   // 8 KB
    int tid = threadIdx.x;
    int lane = tid & 63;
    int og = __builtin_amdgcn_readfirstlane(tid >> 6);   // 0..7, wave-uniform
    int idx0 = blockIdx.x * 64;
    int b = idx0 >> 12, p0 = idx0 & 4095;
    const float* fb = fm + (size_t)b * CFM * 4096 + p0;
    int sc = tid >> 4, spq = tid & 15;                   // staging coords
    const float* saddr = fb + (size_t)sc * 4096 + spq * 4;

    float acc[8];
#pragma unroll
    for (int o = 0; o < 8; o++) acc[o] = 0.f;

    float4 nxt = *(const float4*)saddr;                  // preload chunk 0
    for (int cc = 0; cc < CFM; cc += 32) {
        *(float4*)&ftile[sc][spq * 4] = nxt;             // vmcnt waits here only
        __syncthreads();                                 // tile ready
        if (cc + 32 < CFM)                               // issue next chunk NOW
            nxt = *(const float4*)(saddr + (size_t)(cc + 32) * 4096);
#pragma unroll 8
        for (int c = 0; c < 32; c++) {
            float fv = ftile[c][lane];
            const float4* w4 = (const float4*)(cwT + (cc + c) * 64 + og * 8);
            float4 wa = w4[0], wb = w4[1];
            float w[8] = {wa.x, wa.y, wa.z, wa.w, wb.x, wb.y, wb.z, wb.w};
#pragma unroll
            for (int o = 0; o < 8; o++) acc[o] = fmaf(fv, w[o], acc[o]);
        }
        __syncthreads();                                 // reads done before rewrite
    }
    // pack 8 bf16 (16 B) per thread
    uint_t pk[4];
#pragma unroll
    for (int j = 0; j < 4; j++)
        pk[j] = (uint_t)f2b(acc[2 * j]) | ((uint_t)f2b(acc[2 * j + 1]) << 16);
    uint4* outp = (uint4*)(pf + (size_t)(idx0 + lane) * 64 + og * 8);
    outp[0] = make_uint4(pk[0], pk[1], pk[2], pk[3]);
}

// per-vertex projection + depth visibility + feature bilinear -> xfeat[v][b][64] (bf16)
__global__ void k_sample(const float* __restrict__ depth, const ushort_t* __restrict__ pf,
                         const float* __restrict__ verts, const float* __restrict__ fz,
                         const float* __restrict__ cz, const float* __restrict__ convb,
                         ushort_t* __restrict__ xfeat) {
    int t = blockIdx.x * 256 + threadIdx.x;
    int gid = t >> 4;                 // b*NV+v
    int ln = t & 15;
    int b = gid / NV;
    int v = gid - b * NV;
    const float* vp = verts + (size_t)gid * 3;
    float vx = vp[0], vy = vp[1], vz = vp[2];
    float fzb = fz[b], czb = cz[2 * b];
    float gx = fzb * vx + czb;
    float gy = fzb * vy + czb;
    float gz = fzb * (vz + 100.f);

    float px = (gx + 1.f) * 64.f - 0.5f;
    float py = (gy + 1.f) * 64.f - 0.5f;
    float fx0 = floorf(px), fy0 = floorf(py);
    float wx1 = px - fx0, wy1 = py - fy0, wx0 = 1.f - wx1, wy0 = 1.f - wy1;
    int x0 = (int)fx0, y0 = (int)fy0;
    const float* dmb = depth + (size_t)b * 128 * 128;
    float d00 = 0.f, d01 = 0.f, d10 = 0.f, d11 = 0.f;
    bool X0 = (x0 >= 0 && x0 < 128), X1 = (x0 + 1 >= 0 && x0 + 1 < 128);
    bool Y0 = (y0 >= 0 && y0 < 128), Y1 = (y0 + 1 >= 0 && y0 + 1 < 128);
    int xa = min(max(x0, 0), 127), xb = min(max(x0 + 1, 0), 127);
    int ya = min(max(y0, 0), 127), yb = min(max(y0 + 1, 0), 127);
    if (Y0 && X0) d00 = dmb[ya * 128 + xa];
    if (Y0 && X1) d01 = dmb[ya * 128 + xb];
    if (Y1 && X0) d10 = dmb[yb * 128 + xa];
    if (Y1 && X1) d11 = dmb[yb * 128 + xb];
    float sd = d00 * wy0 * wx0 + d01 * wy0 * wx1 + d10 * wy1 * wx0 + d11 * wy1 * wx1;
    float vis = (fabsf(sd - gz) < FEPS) ? 1.f : 0.f;

    float qx = (gx + 1.f) * 32.f - 0.5f;
    float qy = (gy + 1.f) * 32.f - 0.5f;
    float gx0 = floorf(qx), gy0 = floorf(qy);
    float ax1 = qx - gx0, ay1 = qy - gy0, ax0 = 1.f - ax1, ay0 = 1.f - ay1;
    int cx0 = (int)gx0, cy0 = (int)gy0;
    bool FX0 = (cx0 >= 0 && cx0 < 64), FX1 = (cx0 + 1 >= 0 && cx0 + 1 < 64);
    bool FY0 = (cy0 >= 0 && cy0 < 64), FY1 = (cy0 + 1 >= 0 && cy0 + 1 < 64);
    int fxa = min(max(cx0, 0), 63), fxb = min(max(cx0 + 1, 0), 63);
    int fya = min(max(cy0, 0), 63), fyb = min(max(cy0 + 1, 0), 63);
    float m00 = (FY0 && FX0) ? ay0 * ax0 : 0.f;
    float m01 = (FY0 && FX1) ? ay0 * ax1 : 0.f;
    float m10 = (FY1 && FX0) ? ay1 * ax0 : 0.f;
    float m11 = (FY1 && FX1) ? ay1 * ax1 : 0.f;
    const ushort_t* pfb = pf + (size_t)b * 4096 * 64;
    const ushort_t* p00 = pfb + ((size_t)fya * 64 + fxa) * 64;
    const ushort_t* p01 = pfb + ((size_t)fya * 64 + fxb) * 64;
    const ushort_t* p10 = pfb + ((size_t)fyb * 64 + fxa) * 64;
    const ushort_t* p11 = pfb + ((size_t)fyb * 64 + fxb) * 64;

    ushort_t* xr = xfeat + ((size_t)v * NB + b) * 64;
#pragma unroll
    for (int j = 0; j < 4; j++) {
        int c = ln + 16 * j;
        if (c < CU) {
            float val = m00 * b2f(p00[c]) + m01 * b2f(p01[c])
                      + m10 * b2f(p10[c]) + m11 * b2f(p11[c]);
            xr[c] = f2b(vis * val + convb[c]);
        } else {
            xr[c] = f2b(vp[c - CU]);
        }
    }
}

// ---- CSR build ----
__global__ void k_count(const int* __restrict__ erow, int* __restrict__ counts) {
    int e = blockIdx.x * 256 + threadIdx.x;
    if (e < NE) atomicAdd(&counts[erow[e]], 1);
}

__global__ void k_scan(const int* __restrict__ counts, int* __restrict__ offs) {
    __shared__ int part[1024];
    int t = threadIdx.x;
    int base = t * 12;
    int local[12];
    int s = 0;
#pragma unroll
    for (int i = 0; i < 12; i++) { local[i] = s; s += counts[base + i]; }
    part[t] = s;
    __syncthreads();
    for (int off = 1; off < 1024; off <<= 1) {
        int v = (t >= off) ? part[t - off] : 0;
        __syncthreads();
        part[t] += v;
        __syncthreads();
    }
    int prefix = part[t] - s;   // exclusive
#pragma unroll
    for (int i = 0; i < 12; i++) offs[base + i] = prefix + local[i];
}

__global__ void k_fill(const int* __restrict__ erow, const int* __restrict__ ecol,
                       const int* __restrict__ offs, int* __restrict__ cursor,
                       int* __restrict__ csr) {
    int e = blockIdx.x * 256 + threadIdx.x;
    if (e >= NE) return;
    int r = erow[e];
    int pos = offs[r] + atomicAdd(&cursor[r], 1);
    csr[pos] = ecol[e];
}

// gather-agg: xfeat row (512 bf16 = 1 KB) per edge; one wave per dest vertex
__global__ void k_agg1(const int* __restrict__ counts, const int* __restrict__ offs,
                       const int* __restrict__ csr, const ushort_t* __restrict__ xfeat,
                       float* __restrict__ agg1d) {
    int wid = (blockIdx.x * 256 + threadIdx.x) >> 6;   // vertex
    int l = threadIdx.x & 63;
    if (wid >= NV) return;
    int beg = offs[wid], n = counts[wid];
    float a[8];
#pragma unroll
    for (int t = 0; t < 8; t++) a[t] = 0.f;
    for (int j = 0; j < n; j++) {
        int c = csr[beg + j];
        ushort8v u = *(const ushort8v*)(xfeat + (size_t)c * 512 + l * 8);
#pragma unroll
        for (int t = 0; t < 8; t++) a[t] += b2f(u[t]);
    }
    float dinv = 1.f / fmaxf((float)n, 1.f);
    float4* dst = (float4*)(agg1d + (size_t)wid * 512 + l * 8);
    dst[0] = make_float4(a[0] * dinv, a[1] * dinv, a[2] * dinv, a[3] * dinv);
    dst[1] = make_float4(a[4] * dinv, a[5] * dinv, a[6] * dinv, a[7] * dinv);
}

// fused MLP: block = 256 = 64 rows x 4 hidden-chunk WAVES (chunk wave-uniform ->
// all weights via s_load). 2-phase cross-wave reduction; smem union 18944 B.
__global__ __launch_bounds__(256) void k_mlp(
        const float* __restrict__ agg1d, const float* __restrict__ W1,
        const float* __restrict__ b1, const float* __restrict__ W2,
        const float* __restrict__ Wdv, const float* __restrict__ verts,
        ushort_t* __restrict__ y2, float* __restrict__ out) {
    __shared__ float smem[2 * 64 * 37];   // 18944 B; xl (4160 f) aliases front
    float* xl = smem;                     // [64][65], phase 1
    float* part2 = smem;                  // [2][64][37], phase 2
    int tid = threadIdx.x;
    int lane = tid & 63;
    int w = __builtin_amdgcn_readfirstlane(tid >> 6);   // chunk 0..3, wave-uniform
    int base = blockIdx.x * 64;          // 1536 blocks x 64 rows

    // stage x: thread t loads 16 consecutive floats (block reads 16 KB contiguous)
    {
        int r = tid >> 2, seg = (tid & 3) * 16;
        const float4* src = (const float4*)(agg1d + (size_t)base * 64 + tid * 16);
        float* dst = xl + r * 65 + seg;
#pragma unroll
        for (int i = 0; i < 4; i++) {
            float4 u = src[i];
            dst[4 * i + 0] = u.x; dst[4 * i + 1] = u.y;
            dst[4 * i + 2] = u.z; dst[4 * i + 3] = u.w;
        }
    }
    __syncthreads();

    // GEMM1: h[j] = relu(sum_k x[k] * W1[k][w*32+j] + b1[w*32+j])
    float h[32];
    {
        const float* bp = b1 + w * 32;
#pragma unroll
        for (int j = 0; j < 32; j++) h[j] = bp[j];
    }
    const float* xrow = xl + lane * 65;
#pragma unroll 8
    for (int k = 0; k < 64; k++) {
        float xv = xrow[k];
        const float* wk = W1 + k * 128 + w * 32;   // uniform -> s_load
#pragma unroll
        for (int j = 0; j < 32; j++) h[j] = fmaf(xv, wk[j], h[j]);
    }
#pragma unroll
    for (int j = 0; j < 32; j++) h[j] = fmaxf(h[j], 0.f);

    // GEMM2 partial: this wave's 32 hidden rows of W2/Wdv
    float acc2[35];
#pragma unroll
    for (int j = 0; j < 35; j++) acc2[j] = 0.f;
    const float* w2p = W2 + (size_t)(w * 32) * 32;
    const float* wdp = Wdv + (size_t)(w * 32) * 3;
#pragma unroll 4
    for (int kc = 0; kc < 32; kc++) {
        float hv = h[kc];
#pragma unroll
        for (int j = 0; j < 32; j++)
            acc2[j] = fmaf(hv, w2p[kc * 32 + j], acc2[j]);
        acc2[32] = fmaf(hv, wdp[kc * 3 + 0], acc2[32]);
        acc2[33] = fmaf(hv, wdp[kc * 3 + 1], acc2[33]);
        acc2[34] = fmaf(hv, wdp[kc * 3 + 2], acc2[34]);
    }
    __syncthreads();   // xl reads done -> smem becomes part2

    // phase A: waves 2,3 publish
    if (w >= 2) {
        float* pp = part2 + ((size_t)(w - 2) * 64 + lane) * 37;
#pragma unroll
        for (int j = 0; j < 35; j++) pp[j] = acc2[j];
    }
    __syncthreads();
    // phase B: waves 0,1 accumulate their partner
    if (w < 2) {
        const float* pp = part2 + ((size_t)w * 64 + lane) * 37;
#pragma unroll
        for (int j = 0; j < 35; j++) acc2[j] += pp[j];
    }
    __syncthreads();   // WAR: wave 0's reads of part2[0] done before wave 1 overwrites
    // phase C: wave 1 publishes
    if (w == 1) {
        float* pp = part2 + (size_t)lane * 37;
#pragma unroll
        for (int j = 0; j < 35; j++) pp[j] = acc2[j];
    }
    __syncthreads();
    // phase D: wave 0 finishes in registers
    if (w == 0) {
        const float* pp = part2 + (size_t)lane * 37;
#pragma unroll
        for (int j = 0; j < 35; j++) acc2[j] += pp[j];
        int row = base + lane;
        uint_t pk[16];
#pragma unroll
        for (int j = 0; j < 16; j++)
            pk[j] = (uint_t)f2b(acc2[2 * j]) | ((uint_t)f2b(acc2[2 * j + 1]) << 16);
        uint4* yp = (uint4*)(y2 + (size_t)row * 32);
#pragma unroll
        for (int j = 0; j < 4; j++)
            yp[j] = make_uint4(pk[4 * j], pk[4 * j + 1], pk[4 * j + 2], pk[4 * j + 3]);
        float e0 = acc2[32], e1 = acc2[33], e2 = acc2[34];
        int v = row >> 3, b = row & 7;
        const float* vp = verts + ((size_t)b * NV + v) * 3;
        float* orow = out + ((size_t)b * NV + v) * 38;
        orow[32] = (vp[0] + e0) * 1000.f;
        orow[33] = (vp[1] + e1) * 1000.f;
        orow[34] = (vp[2] + e2) * 1000.f;
        orow[35] = e0 * 1000.f;
        orow[36] = e1 * 1000.f;
        orow[37] = e2 * 1000.f;
    }
}

// gather-agg over y2 (256 bf16 = 512 B per vertex-row); write out[0..31]
__global__ void k_agg2(const int* __restrict__ counts, const int* __restrict__ offs,
                       const int* __restrict__ csr, const ushort_t* __restrict__ y2,
                       float* __restrict__ out) {
    int wid = (blockIdx.x * 256 + threadIdx.x) >> 6;   // vertex
    int l = threadIdx.x & 63;
    if (wid >= NV) return;
    int beg = offs[wid], n = counts[wid];
    float a[4];
#pragma unroll
    for (int t = 0; t < 4; t++) a[t] = 0.f;
    for (int j = 0; j < n; j++) {
        int c = csr[beg + j];
        ushort4v u = *(const ushort4v*)(y2 + (size_t)c * 256 + l * 4);
#pragma unroll
        for (int t = 0; t < 4; t++) a[t] += b2f(u[t]);
    }
    float dinv = 1.f / fmaxf((float)n, 1.f);
    int b = l >> 3, o = (l & 7) * 4;
    float* orow = out + ((size_t)b * NV + wid) * 38 + o;
    orow[0] = a[0] * dinv;
    orow[1] = a[1] * dinv;
    orow[2] = a[2] * dinv;
    orow[3] = a[3] * dinv;
}

extern "C" void kernel_launch(void* const* d_in, const int* in_sizes, int n_in,
                              void* d_out, int out_size, void* d_ws, size_t ws_size,
                              hipStream_t stream) {
    const float* fm  = (const float*)d_in[0];
    const float* dm  = (const float*)d_in[1];
    const float* vt  = (const float*)d_in[2];
    const float* fz  = (const float*)d_in[3];
    const float* cz  = (const float*)d_in[4];
    const float* cw  = (const float*)d_in[5];
    const float* cb  = (const float*)d_in[6];
    const float* W1  = (const float*)d_in[7];
    const float* b1  = (const float*)d_in[8];
    const float* W2  = (const float*)d_in[9];
    const float* Wdv = (const float*)d_in[10];
    const int* erow  = (const int*)d_in[11];
    const int* ecol  = (const int*)d_in[12];
    float* out = (float*)d_out;

    float* ws    = (float*)d_ws;
    float* agg1d = ws;                            // 6291456 f
    float* cwT   = agg1d + 6291456;               // 24576 f
    ushort_t* pf = (ushort_t*)(cwT + 24576);      // 2097152 bf16 (1048576 f)
    ushort_t* xfeat = (ushort_t*)((float*)pf + 1048576);   // 6291456 bf16
    ushort_t* y2 = (ushort_t*)((float*)xfeat + 3145728);   // 3145728 bf16
    int* counts  = (int*)((float*)y2 + 1572864);  // 12288
    int* offs    = counts + 12288;
    int* cursor  = offs + 12288;
    int* csr     = cursor + 12288;                // 147456

    hipMemsetAsync(counts, 0, 12288 * sizeof(int), stream);
    hipMemsetAsync(cursor, 0, 12288 * sizeof(int), stream);

    k_wt<<<96, 256, 0, stream>>>(cw, cwT);
    k_conv<<<512, 512, 0, stream>>>(fm, cwT, pf);
    k_sample<<<6144, 256, 0, stream>>>(dm, pf, vt, fz, cz, cb, xfeat);
    k_count<<<576, 256, 0, stream>>>(erow, counts);
    k_scan<<<1, 1024, 0, stream>>>(counts, offs);
    k_fill<<<576, 256, 0, stream>>>(erow, ecol, offs, cursor, csr);
    k_agg1<<<3072, 256, 0, stream>>>(counts, offs, csr, xfeat, agg1d);
    k_mlp<<<1536, 256, 0, stream>>>(agg1d, W1, b1, W2, Wdv, vt, y2, out);
    k_agg2<<<3072, 256, 0, stream>>>(counts, offs, csr, y2, out);
}

// Round 15
// 149.330 us; speedup vs baseline: 1.6028x; 1.0900x over previous
//
#include <hip/hip_runtime.h>

#define NB 8
#define NV 12288
#define NE 147456
#define CFM 384
#define CU 61
#define FEPS 0.005f

typedef unsigned short ushort_t;
typedef unsigned int uint_t;
typedef __attribute__((ext_vector_type(8))) unsigned short ushort8v;
typedef __attribute__((ext_vector_type(4))) unsigned short ushort4v;

__device__ inline float b2f(ushort_t u) {
    return __uint_as_float(((uint_t)u) << 16);
}
__device__ inline ushort_t f2b(float f) {   // round-nearest-even
    uint_t u = __float_as_uint(f);
    return (ushort_t)((u + 0x7fffu + ((u >> 16) & 1u)) >> 16);
}

// transpose conv_w (61,384) -> cwT (384,64), zero-pad o>=61
__global__ void k_wt(const float* __restrict__ cw, float* __restrict__ cwT) {
    int idx = blockIdx.x * 256 + threadIdx.x;
    if (idx >= CFM * 64) return;
    int c = idx >> 6, o = idx & 63;
    cwT[idx] = (o < CU) ? cw[o * CFM + c] : 0.f;
}

// pf[b][p][o] = sum_c cwT[c][o] * fm[b][c][p]  (pf stored bf16)
// block = 512 = 64 positions x 8 og-waves of 8 outputs; T14 async-STAGE.
__global__ __launch_bounds__(512) void k_conv(const float* __restrict__ fm,
                                              const float* __restrict__ cwT,
                                              ushort_t* __restrict__ pf) {
    __shared__ float ftile[32][64];   // 8 KB
    int tid = threadIdx.x;
    int lane = tid & 63;
    int og = __builtin_amdgcn_readfirstlane(tid >> 6);   // 0..7, wave-uniform
    int idx0 = blockIdx.x * 64;
    int b = idx0 >> 12, p0 = idx0 & 4095;
    const float* fb = fm + (size_t)b * CFM * 4096 + p0;
    int sc = tid >> 4, spq = tid & 15;                   // staging coords
    const float* saddr = fb + (size_t)sc * 4096 + spq * 4;

    float acc[8];
#pragma unroll
    for (int o = 0; o < 8; o++) acc[o] = 0.f;

    float4 nxt = *(const float4*)saddr;                  // preload chunk 0
    for (int cc = 0; cc < CFM; cc += 32) {
        *(float4*)&ftile[sc][spq * 4] = nxt;             // vmcnt waits here only
        __syncthreads();                                 // tile ready
        if (cc + 32 < CFM)                               // issue next chunk NOW
            nxt = *(const float4*)(saddr + (size_t)(cc + 32) * 4096);
#pragma unroll 8
        for (int c = 0; c < 32; c++) {
            float fv = ftile[c][lane];
            const float4* w4 = (const float4*)(cwT + (cc + c) * 64 + og * 8);
            float4 wa = w4[0], wb = w4[1];
            float w[8] = {wa.x, wa.y, wa.z, wa.w, wb.x, wb.y, wb.z, wb.w};
#pragma unroll
            for (int o = 0; o < 8; o++) acc[o] = fmaf(fv, w[o], acc[o]);
        }
        __syncthreads();                                 // reads done before rewrite
    }
    uint_t pk[4];
#pragma unroll
    for (int j = 0; j < 4; j++)
        pk[j] = (uint_t)f2b(acc[2 * j]) | ((uint_t)f2b(acc[2 * j + 1]) << 16);
    uint4* outp = (uint4*)(pf + (size_t)(idx0 + lane) * 64 + og * 8);
    outp[0] = make_uint4(pk[0], pk[1], pk[2], pk[3]);
}

// per-vertex projection + depth visibility + feature bilinear -> xfeat[v][b][64] (bf16)
__global__ void k_sample(const float* __restrict__ depth, const ushort_t* __restrict__ pf,
                         const float* __restrict__ verts, const float* __restrict__ fz,
                         const float* __restrict__ cz, const float* __restrict__ convb,
                         ushort_t* __restrict__ xfeat) {
    int t = blockIdx.x * 256 + threadIdx.x;
    int gid = t >> 4;                 // b*NV+v
    int ln = t & 15;
    int b = gid / NV;
    int v = gid - b * NV;
    const float* vp = verts + (size_t)gid * 3;
    float vx = vp[0], vy = vp[1], vz = vp[2];
    float fzb = fz[b], czb = cz[2 * b];
    float gx = fzb * vx + czb;
    float gy = fzb * vy + czb;
    float gz = fzb * (vz + 100.f);

    float px = (gx + 1.f) * 64.f - 0.5f;
    float py = (gy + 1.f) * 64.f - 0.5f;
    float fx0 = floorf(px), fy0 = floorf(py);
    float wx1 = px - fx0, wy1 = py - fy0, wx0 = 1.f - wx1, wy0 = 1.f - wy1;
    int x0 = (int)fx0, y0 = (int)fy0;
    const float* dmb = depth + (size_t)b * 128 * 128;
    float d00 = 0.f, d01 = 0.f, d10 = 0.f, d11 = 0.f;
    bool X0 = (x0 >= 0 && x0 < 128), X1 = (x0 + 1 >= 0 && x0 + 1 < 128);
    bool Y0 = (y0 >= 0 && y0 < 128), Y1 = (y0 + 1 >= 0 && y0 + 1 < 128);
    int xa = min(max(x0, 0), 127), xb = min(max(x0 + 1, 0), 127);
    int ya = min(max(y0, 0), 127), yb = min(max(y0 + 1, 0), 127);
    if (Y0 && X0) d00 = dmb[ya * 128 + xa];
    if (Y0 && X1) d01 = dmb[ya * 128 + xb];
    if (Y1 && X0) d10 = dmb[yb * 128 + xa];
    if (Y1 && X1) d11 = dmb[yb * 128 + xb];
    float sd = d00 * wy0 * wx0 + d01 * wy0 * wx1 + d10 * wy1 * wx0 + d11 * wy1 * wx1;
    float vis = (fabsf(sd - gz) < FEPS) ? 1.f : 0.f;

    float qx = (gx + 1.f) * 32.f - 0.5f;
    float qy = (gy + 1.f) * 32.f - 0.5f;
    float gx0 = floorf(qx), gy0 = floorf(qy);
    float ax1 = qx - gx0, ay1 = qy - gy0, ax0 = 1.f - ax1, ay0 = 1.f - ay1;
    int cx0 = (int)gx0, cy0 = (int)gy0;
    bool FX0 = (cx0 >= 0 && cx0 < 64), FX1 = (cx0 + 1 >= 0 && cx0 + 1 < 64);
    bool FY0 = (cy0 >= 0 && cy0 < 64), FY1 = (cy0 + 1 >= 0 && cy0 + 1 < 64);
    int fxa = min(max(cx0, 0), 63), fxb = min(max(cx0 + 1, 0), 63);
    int fya = min(max(cy0, 0), 63), fyb = min(max(cy0 + 1, 0), 63);
    float m00 = (FY0 && FX0) ? ay0 * ax0 : 0.f;
    float m01 = (FY0 && FX1) ? ay0 * ax1 : 0.f;
    float m10 = (FY1 && FX0) ? ay1 * ax0 : 0.f;
    float m11 = (FY1 && FX1) ? ay1 * ax1 : 0.f;
    const ushort_t* pfb = pf + (size_t)b * 4096 * 64;
    const ushort_t* p00 = pfb + ((size_t)fya * 64 + fxa) * 64;
    const ushort_t* p01 = pfb + ((size_t)fya * 64 + fxb) * 64;
    const ushort_t* p10 = pfb + ((size_t)fyb * 64 + fxa) * 64;
    const ushort_t* p11 = pfb + ((size_t)fyb * 64 + fxb) * 64;

    ushort_t* xr = xfeat + ((size_t)v * NB + b) * 64;
#pragma unroll
    for (int j = 0; j < 4; j++) {
        int c = ln + 16 * j;
        if (c < CU) {
            float val = m00 * b2f(p00[c]) + m01 * b2f(p01[c])
                      + m10 * b2f(p10[c]) + m11 * b2f(p11[c]);
            xr[c] = f2b(vis * val + convb[c]);
        } else {
            xr[c] = f2b(vp[c - CU]);
        }
    }
}

// ---- CSR build ----
__global__ void k_count(const int* __restrict__ erow, int* __restrict__ counts) {
    int e = blockIdx.x * 256 + threadIdx.x;
    if (e < NE) atomicAdd(&counts[erow[e]], 1);
}

__global__ void k_scan(const int* __restrict__ counts, int* __restrict__ offs) {
    __shared__ int part[1024];
    int t = threadIdx.x;
    int base = t * 12;
    int local[12];
    int s = 0;
#pragma unroll
    for (int i = 0; i < 12; i++) { local[i] = s; s += counts[base + i]; }
    part[t] = s;
    __syncthreads();
    for (int off = 1; off < 1024; off <<= 1) {
        int v = (t >= off) ? part[t - off] : 0;
        __syncthreads();
        part[t] += v;
        __syncthreads();
    }
    int prefix = part[t] - s;   // exclusive
#pragma unroll
    for (int i = 0; i < 12; i++) offs[base + i] = prefix + local[i];
}

__global__ void k_fill(const int* __restrict__ erow, const int* __restrict__ ecol,
                       const int* __restrict__ offs, int* __restrict__ cursor,
                       int* __restrict__ csr) {
    int e = blockIdx.x * 256 + threadIdx.x;
    if (e >= NE) return;
    int r = erow[e];
    int pos = offs[r] + atomicAdd(&cursor[r], 1);
    csr[pos] = ecol[e];
}

// FUSED gather + MLP: block = 256 = 8 vertices (64 rows) x 4 waves.
// Phase 0: wave w gathers vertices vbase+2w, vbase+2w+1 from xfeat (16B/lane,
//   csr wave-uniform -> s_load) and writes averaged rows DIRECTLY into xl LDS
//   -- agg1d (50 MB HBM round-trip) eliminated.
// Phase 1/2: R14's proven GEMM1 / GEMM2 + 2-phase cross-wave reduction,
//   smem union 18944 B (xl[64][65] then part2[2][64][37]).
__global__ __launch_bounds__(256) void k_gmlp(
        const int* __restrict__ counts, const int* __restrict__ offs,
        const int* __restrict__ csr, const ushort_t* __restrict__ xfeat,
        const float* __restrict__ W1, const float* __restrict__ b1,
        const float* __restrict__ W2, const float* __restrict__ Wdv,
        const float* __restrict__ verts, ushort_t* __restrict__ y2,
        float* __restrict__ out) {
    __shared__ float smem[2 * 64 * 37];   // 18944 B
    float* xl = smem;                     // [64][65], phases 0-1
    float* part2 = smem;                  // [2][64][37], phase 2
    int tid = threadIdx.x;
    int lane = tid & 63;
    int w = __builtin_amdgcn_readfirstlane(tid >> 6);   // 0..3, wave-uniform
    int vbase = blockIdx.x * 8;          // 1536 blocks x 8 vertices

    // ---- phase 0: gather 2 vertices per wave into xl
#pragma unroll
    for (int s = 0; s < 2; s++) {
        int vid = vbase + 2 * w + s;     // wave-uniform
        int beg = offs[vid], n = counts[vid];
        float a[8];
#pragma unroll
        for (int t = 0; t < 8; t++) a[t] = 0.f;
        for (int j = 0; j < n; j++) {
            int c = csr[beg + j];        // wave-uniform -> s_load
            ushort8v u = *(const ushort8v*)(xfeat + (size_t)c * 512 + lane * 8);
#pragma unroll
            for (int t = 0; t < 8; t++) a[t] += b2f(u[t]);
        }
        float dinv = 1.f / fmaxf((float)n, 1.f);
        // lane covers row (2w+s)*8 + (lane>>3), cols (lane&7)*8 .. +8
        float* dst = xl + ((2 * w + s) * 8 + (lane >> 3)) * 65 + (lane & 7) * 8;
#pragma unroll
        for (int t = 0; t < 8; t++) dst[t] = a[t] * dinv;
    }
    __syncthreads();

    // ---- phase 1: GEMM1  h = relu(x @ W1 + b1)
    float h[32];
    {
        const float* bp = b1 + w * 32;
#pragma unroll
        for (int j = 0; j < 32; j++) h[j] = bp[j];
    }
    const float* xrow = xl + lane * 65;
#pragma unroll 8
    for (int k = 0; k < 64; k++) {
        float xv = xrow[k];
        const float* wk = W1 + k * 128 + w * 32;   // uniform -> s_load
#pragma unroll
        for (int j = 0; j < 32; j++) h[j] = fmaf(xv, wk[j], h[j]);
    }
#pragma unroll
    for (int j = 0; j < 32; j++) h[j] = fmaxf(h[j], 0.f);

    // GEMM2 partial: this wave's 32 hidden rows of W2/Wdv
    float acc2[35];
#pragma unroll
    for (int j = 0; j < 35; j++) acc2[j] = 0.f;
    const float* w2p = W2 + (size_t)(w * 32) * 32;
    const float* wdp = Wdv + (size_t)(w * 32) * 3;
#pragma unroll 4
    for (int kc = 0; kc < 32; kc++) {
        float hv = h[kc];
#pragma unroll
        for (int j = 0; j < 32; j++)
            acc2[j] = fmaf(hv, w2p[kc * 32 + j], acc2[j]);
        acc2[32] = fmaf(hv, wdp[kc * 3 + 0], acc2[32]);
        acc2[33] = fmaf(hv, wdp[kc * 3 + 1], acc2[33]);
        acc2[34] = fmaf(hv, wdp[kc * 3 + 2], acc2[34]);
    }
    __syncthreads();   // xl reads done -> smem becomes part2

    // ---- phase 2: 2-phase cross-wave reduction (R14 structure, unchanged)
    if (w >= 2) {
        float* pp = part2 + ((size_t)(w - 2) * 64 + lane) * 37;
#pragma unroll
        for (int j = 0; j < 35; j++) pp[j] = acc2[j];
    }
    __syncthreads();
    if (w < 2) {
        const float* pp = part2 + ((size_t)w * 64 + lane) * 37;
#pragma unroll
        for (int j = 0; j < 35; j++) acc2[j] += pp[j];
    }
    __syncthreads();   // WAR before wave 1 overwrites
    if (w == 1) {
        float* pp = part2 + (size_t)lane * 37;
#pragma unroll
        for (int j = 0; j < 35; j++) pp[j] = acc2[j];
    }
    __syncthreads();
    if (w == 0) {
        const float* pp = part2 + (size_t)lane * 37;
#pragma unroll
        for (int j = 0; j < 35; j++) acc2[j] += pp[j];
        int row = vbase * 8 + lane;     // = v*8+b, vertex-major
        uint_t pk[16];
#pragma unroll
        for (int j = 0; j < 16; j++)
            pk[j] = (uint_t)f2b(acc2[2 * j]) | ((uint_t)f2b(acc2[2 * j + 1]) << 16);
        uint4* yp = (uint4*)(y2 + (size_t)row * 32);
#pragma unroll
        for (int j = 0; j < 4; j++)
            yp[j] = make_uint4(pk[4 * j], pk[4 * j + 1], pk[4 * j + 2], pk[4 * j + 3]);
        float e0 = acc2[32], e1 = acc2[33], e2 = acc2[34];
        int v = row >> 3, b = row & 7;
        const float* vp = verts + ((size_t)b * NV + v) * 3;
        float* orow = out + ((size_t)b * NV + v) * 38;
        orow[32] = (vp[0] + e0) * 1000.f;
        orow[33] = (vp[1] + e1) * 1000.f;
        orow[34] = (vp[2] + e2) * 1000.f;
        orow[35] = e0 * 1000.f;
        orow[36] = e1 * 1000.f;
        orow[37] = e2 * 1000.f;
    }
}

// gather-agg over y2 (256 bf16 = 512 B per vertex-row); write out[0..31]
__global__ void k_agg2(const int* __restrict__ counts, const int* __restrict__ offs,
                       const int* __restrict__ csr, const ushort_t* __restrict__ y2,
                       float* __restrict__ out) {
    int wid = (blockIdx.x * 256 + threadIdx.x) >> 6;   // vertex
    int l = threadIdx.x & 63;
    if (wid >= NV) return;
    int beg = offs[wid], n = counts[wid];
    float a[4];
#pragma unroll
    for (int t = 0; t < 4; t++) a[t] = 0.f;
    for (int j = 0; j < n; j++) {
        int c = csr[beg + j];
        ushort4v u = *(const ushort4v*)(y2 + (size_t)c * 256 + l * 4);
#pragma unroll
        for (int t = 0; t < 4; t++) a[t] += b2f(u[t]);
    }
    float dinv = 1.f / fmaxf((float)n, 1.f);
    int b = l >> 3, o = (l & 7) * 4;
    float* orow = out + ((size_t)b * NV + wid) * 38 + o;
    orow[0] = a[0] * dinv;
    orow[1] = a[1] * dinv;
    orow[2] = a[2] * dinv;
    orow[3] = a[3] * dinv;
}

extern "C" void kernel_launch(void* const* d_in, const int* in_sizes, int n_in,
                              void* d_out, int out_size, void* d_ws, size_t ws_size,
                              hipStream_t stream) {
    const float* fm  = (const float*)d_in[0];
    const float* dm  = (const float*)d_in[1];
    const float* vt  = (const float*)d_in[2];
    const float* fz  = (const float*)d_in[3];
    const float* cz  = (const float*)d_in[4];
    const float* cw  = (const float*)d_in[5];
    const float* cb  = (const float*)d_in[6];
    const float* W1  = (const float*)d_in[7];
    const float* b1  = (const float*)d_in[8];
    const float* W2  = (const float*)d_in[9];
    const float* Wdv = (const float*)d_in[10];
    const int* erow  = (const int*)d_in[11];
    const int* ecol  = (const int*)d_in[12];
    float* out = (float*)d_out;

    float* ws    = (float*)d_ws;
    float* cwT   = ws;                            // 24576 f
    ushort_t* pf = (ushort_t*)(cwT + 24576);      // 2097152 bf16 (1048576 f)
    ushort_t* xfeat = (ushort_t*)((float*)pf + 1048576);   // 6291456 bf16
    ushort_t* y2 = (ushort_t*)((float*)xfeat + 3145728);   // 3145728 bf16
    int* counts  = (int*)((float*)y2 + 1572864);  // 12288
    int* offs    = counts + 12288;
    int* cursor  = offs + 12288;
    int* csr     = cursor + 12288;                // 147456

    hipMemsetAsync(counts, 0, 12288 * sizeof(int), stream);
    hipMemsetAsync(cursor, 0, 12288 * sizeof(int), stream);

    k_wt<<<96, 256, 0, stream>>>(cw, cwT);
    k_conv<<<512, 512, 0, stream>>>(fm, cwT, pf);
    k_sample<<<6144, 256, 0, stream>>>(dm, pf, vt, fz, cz, cb, xfeat);
    k_count<<<576, 256, 0, stream>>>(erow, counts);
    k_scan<<<1, 1024, 0, stream>>>(counts, offs);
    k_fill<<<576, 256, 0, stream>>>(erow, ecol, offs, cursor, csr);
    k_gmlp<<<1536, 256, 0, stream>>>(counts, offs, csr, xfeat,
                                     W1, b1, W2, Wdv, vt, y2, out);
    k_agg2<<<3072, 256, 0, stream>>>(counts, offs, csr, y2, out);
}

// Round 17
// 143.775 us; speedup vs baseline: 1.6647x; 1.0386x over previous
//
#include <hip/hip_runtime.h>

#define NB 8
#define NV 12288
#define NE 147456
#define CFM 384
#define CU 61
#define FEPS 0.005f

typedef unsigned short ushort_t;
typedef unsigned int uint_t;
typedef __attribute__((ext_vector_type(8))) unsigned short ushort8v;
typedef __attribute__((ext_vector_type(4))) unsigned short ushort4v;

__device__ inline float b2f(ushort_t u) {
    return __uint_as_float(((uint_t)u) << 16);
}
__device__ inline ushort_t f2b(float f) {   // round-nearest-even
    uint_t u = __float_as_uint(f);
    return (ushort_t)((u + 0x7fffu + ((u >> 16) & 1u)) >> 16);
}

// ---- L1: k_wt (blocks 0..47) || k_count (blocks 48..335), 512 thr ----
__global__ __launch_bounds__(512) void kL1(const float* __restrict__ cw,
                                           float* __restrict__ cwT,
                                           const int* __restrict__ erow,
                                           int* __restrict__ counts) {
    if (blockIdx.x < 48) {               // transpose conv_w -> cwT[384][64]
        int idx = blockIdx.x * 512 + threadIdx.x;   // 24576
        int c = idx >> 6, o = idx & 63;
        cwT[idx] = (o < CU) ? cw[o * CFM + c] : 0.f;
    } else {                             // degree count
        int e = (blockIdx.x - 48) * 512 + threadIdx.x;
        if (e < NE) atomicAdd(&counts[erow[e]], 1);
    }
}

// conv body: pf[b][p][o] = sum_c cwT[c][o]*fm[b][c][p], bf16 out.
// 512 thr = 64 pos x 8 og-waves of 8 outputs (s_load weights); T14 prefetch +
// DOUBLE-BUFFERED LDS -> ONE barrier per chunk (R15 had 2; write of chunk k+1
// goes to the other buffer so it can't collide with reads of chunk k).
__device__ void conv_body(int bid, float* smem, const float* __restrict__ fm,
                          const float* __restrict__ cwT, ushort_t* __restrict__ pf) {
    int tid = threadIdx.x;
    int lane = tid & 63;
    int og = __builtin_amdgcn_readfirstlane(tid >> 6);   // 0..7, wave-uniform
    int idx0 = bid * 64;
    int b = idx0 >> 12, p0 = idx0 & 4095;
    const float* fb = fm + (size_t)b * CFM * 4096 + p0;
    int sc = tid >> 4, spq = tid & 15;
    const float* saddr = fb + (size_t)sc * 4096 + spq * 4;

    float acc[8];
#pragma unroll
    for (int o = 0; o < 8; o++) acc[o] = 0.f;

    float4 nxt = *(const float4*)saddr;                  // preload chunk 0
    int buf = 0;
    for (int cc = 0; cc < CFM; cc += 32) {
        float* ftb = smem + buf * 2048;                  // [32][64]
        *(float4*)(ftb + sc * 64 + spq * 4) = nxt;       // vmcnt waits here only
        __syncthreads();                                 // tile ready (single barrier)
        if (cc + 32 < CFM)
            nxt = *(const float4*)(saddr + (size_t)(cc + 32) * 4096);
#pragma unroll 8
        for (int c = 0; c < 32; c++) {
            float fv = ftb[c * 64 + lane];
            const float4* w4 = (const float4*)(cwT + (cc + c) * 64 + og * 8);
            float4 wa = w4[0], wb = w4[1];
            float w[8] = {wa.x, wa.y, wa.z, wa.w, wb.x, wb.y, wb.z, wb.w};
#pragma unroll
            for (int o = 0; o < 8; o++) acc[o] = fmaf(fv, w[o], acc[o]);
        }
        buf ^= 1;                                        // next write -> other buffer
    }
    uint_t pk[4];
#pragma unroll
    for (int j = 0; j < 4; j++)
        pk[j] = (uint_t)f2b(acc[2 * j]) | ((uint_t)f2b(acc[2 * j + 1]) << 16);
    uint4* outp = (uint4*)(pf + (size_t)(idx0 + lane) * 64 + og * 8);
    outp[0] = make_uint4(pk[0], pk[1], pk[2], pk[3]);
}

// scan body: exclusive prefix over 12288 counts; 512 thr x 24 bins
__device__ void scan_body(int* ipart, const int* __restrict__ counts,
                          int* __restrict__ offs) {
    int t = threadIdx.x;
    int base = t * 24;
    int local[24];
    int s = 0;
#pragma unroll
    for (int i = 0; i < 24; i++) { local[i] = s; s += counts[base + i]; }
    ipart[t] = s;
    __syncthreads();
    for (int off = 1; off < 512; off <<= 1) {
        int v = (t >= off) ? ipart[t - off] : 0;
        __syncthreads();
        ipart[t] += v;
        __syncthreads();
    }
    int prefix = ipart[t] - s;   // exclusive
#pragma unroll
    for (int i = 0; i < 24; i++) offs[base + i] = prefix + local[i];
}

// ---- L2: k_scan (block 0) || k_conv (blocks 1..512), 512 thr, 16 KB LDS ----
__global__ __launch_bounds__(512) void kL2(const float* __restrict__ fm,
                                           const float* __restrict__ cwT,
                                           ushort_t* __restrict__ pf,
                                           const int* __restrict__ counts,
                                           int* __restrict__ offs) {
    __shared__ float smem[2 * 32 * 64];   // 16 KB (conv dbuf; scan uses 2 KB)
    if (blockIdx.x == 0) {
        scan_body((int*)smem, counts, offs);
    } else {
        conv_body(blockIdx.x - 1, smem, fm, cwT, pf);
    }
}

// sample body: projection + depth visibility + feature bilinear -> xfeat bf16
__device__ void sample_body(int t, const float* __restrict__ depth,
                            const ushort_t* __restrict__ pf,
                            const float* __restrict__ verts,
                            const float* __restrict__ fz,
                            const float* __restrict__ cz,
                            const float* __restrict__ convb,
                            ushort_t* __restrict__ xfeat) {
    int gid = t >> 4;                 // b*NV+v
    int ln = t & 15;
    int b = gid / NV;
    int v = gid - b * NV;
    const float* vp = verts + (size_t)gid * 3;
    float vx = vp[0], vy = vp[1], vz = vp[2];
    float fzb = fz[b], czb = cz[2 * b];
    float gx = fzb * vx + czb;
    float gy = fzb * vy + czb;
    float gz = fzb * (vz + 100.f);

    float px = (gx + 1.f) * 64.f - 0.5f;
    float py = (gy + 1.f) * 64.f - 0.5f;
    float fx0 = floorf(px), fy0 = floorf(py);
    float wx1 = px - fx0, wy1 = py - fy0, wx0 = 1.f - wx1, wy0 = 1.f - wy1;
    int x0 = (int)fx0, y0 = (int)fy0;
    const float* dmb = depth + (size_t)b * 128 * 128;
    float d00 = 0.f, d01 = 0.f, d10 = 0.f, d11 = 0.f;
    bool X0 = (x0 >= 0 && x0 < 128), X1 = (x0 + 1 >= 0 && x0 + 1 < 128);
    bool Y0 = (y0 >= 0 && y0 < 128), Y1 = (y0 + 1 >= 0 && y0 + 1 < 128);
    int xa = min(max(x0, 0), 127), xb = min(max(x0 + 1, 0), 127);
    int ya = min(max(y0, 0), 127), yb = min(max(y0 + 1, 0), 127);
    if (Y0 && X0) d00 = dmb[ya * 128 + xa];
    if (Y0 && X1) d01 = dmb[ya * 128 + xb];
    if (Y1 && X0) d10 = dmb[yb * 128 + xa];
    if (Y1 && X1) d11 = dmb[yb * 128 + xb];
    float sd = d00 * wy0 * wx0 + d01 * wy0 * wx1 + d10 * wy1 * wx0 + d11 * wy1 * wx1;
    float vis = (fabsf(sd - gz) < FEPS) ? 1.f : 0.f;

    float qx = (gx + 1.f) * 32.f - 0.5f;
    float qy = (gy + 1.f) * 32.f - 0.5f;
    float gx0 = floorf(qx), gy0 = floorf(qy);
    float ax1 = qx - gx0, ay1 = qy - gy0, ax0 = 1.f - ax1, ay0 = 1.f - ay1;
    int icx0 = (int)gx0, icy0 = (int)gy0;
    bool FX0 = (icx0 >= 0 && icx0 < 64), FX1 = (icx0 + 1 >= 0 && icx0 + 1 < 64);
    bool FY0 = (icy0 >= 0 && icy0 < 64), FY1 = (icy0 + 1 >= 0 && icy0 + 1 < 64);
    int fxa = min(max(icx0, 0), 63), fxb = min(max(icx0 + 1, 0), 63);
    int fya = min(max(icy0, 0), 63), fyb = min(max(icy0 + 1, 0), 63);
    float m00 = (FY0 && FX0) ? ay0 * ax0 : 0.f;
    float m01 = (FY0 && FX1) ? ay0 * ax1 : 0.f;
    float m10 = (FY1 && FX0) ? ay1 * ax0 : 0.f;
    float m11 = (FY1 && FX1) ? ay1 * ax1 : 0.f;
    const ushort_t* pfb = pf + (size_t)b * 4096 * 64;
    const ushort_t* p00 = pfb + ((size_t)fya * 64 + fxa) * 64;
    const ushort_t* p01 = pfb + ((size_t)fya * 64 + fxb) * 64;
    const ushort_t* p10 = pfb + ((size_t)fyb * 64 + fxa) * 64;
    const ushort_t* p11 = pfb + ((size_t)fyb * 64 + fxb) * 64;

    ushort_t* xr = xfeat + ((size_t)v * NB + b) * 64;
#pragma unroll
    for (int j = 0; j < 4; j++) {
        int c = ln + 16 * j;
        if (c < CU) {
            float val = m00 * b2f(p00[c]) + m01 * b2f(p01[c])
                      + m10 * b2f(p10[c]) + m11 * b2f(p11[c]);
            xr[c] = f2b(vis * val + convb[c]);
        } else {
            xr[c] = f2b(vp[c - CU]);
        }
    }
}

// ---- L3: k_fill (blocks 0..287) || k_sample (blocks 288..3359), 512 thr ----
__global__ __launch_bounds__(512) void kL3(const int* __restrict__ erow,
                                           const int* __restrict__ ecol,
                                           const int* __restrict__ offs,
                                           int* __restrict__ cursor,
                                           int* __restrict__ csr,
                                           const float* __restrict__ depth,
                                           const ushort_t* __restrict__ pf,
                                           const float* __restrict__ verts,
                                           const float* __restrict__ fz,
                                           const float* __restrict__ cz,
                                           const float* __restrict__ convb,
                                           ushort_t* __restrict__ xfeat) {
    if (blockIdx.x < 288) {
        int e = blockIdx.x * 512 + threadIdx.x;
        if (e < NE) {
            int r = erow[e];
            int pos = offs[r] + atomicAdd(&cursor[r], 1);
            csr[pos] = ecol[e];
        }
    } else {
        int t = (blockIdx.x - 288) * 512 + threadIdx.x;
        sample_body(t, depth, pf, verts, fz, cz, convb, xfeat);
    }
}

// FUSED gather + MLP: block = 256 = 8 vertices (64 rows) x 4 waves.
// Phase 0 INTERLEAVES the wave's two vertex gathers (2 independent load
// chains -> 2x memory-level parallelism in the latency-bound phase).
// Phase 1/2: proven GEMM1/GEMM2 + 2-phase cross-wave reduction (18944 B union).
__global__ __launch_bounds__(256) void k_gmlp(
        const int* __restrict__ counts, const int* __restrict__ offs,
        const int* __restrict__ csr, const ushort_t* __restrict__ xfeat,
        const float* __restrict__ W1, const float* __restrict__ b1,
        const float* __restrict__ W2, const float* __restrict__ Wdv,
        const float* __restrict__ verts, ushort_t* __restrict__ y2,
        float* __restrict__ out) {
    __shared__ float smem[2 * 64 * 37];   // 18944 B
    float* xl = smem;                     // [64][65], phases 0-1
    float* part2 = smem;                  // [2][64][37], phase 2
    int tid = threadIdx.x;
    int lane = tid & 63;
    int w = __builtin_amdgcn_readfirstlane(tid >> 6);   // 0..3, wave-uniform
    int vbase = blockIdx.x * 8;          // 1536 blocks x 8 vertices

    // ---- phase 0: interleaved gather of vertices vid, vid+1
    {
        int vid = vbase + 2 * w;         // wave-uniform
        int beg0 = offs[vid], n0 = counts[vid];
        int beg1 = offs[vid + 1], n1 = counts[vid + 1];
        float a0[8], a1[8];
#pragma unroll
        for (int t = 0; t < 8; t++) { a0[t] = 0.f; a1[t] = 0.f; }
        int nmax = max(n0, n1);
        for (int j = 0; j < nmax; j++) {
            if (j < n0) {                // wave-uniform branch
                int c = csr[beg0 + j];   // s_load
                ushort8v u = *(const ushort8v*)(xfeat + (size_t)c * 512 + lane * 8);
#pragma unroll
                for (int t = 0; t < 8; t++) a0[t] += b2f(u[t]);
            }
            if (j < n1) {
                int c = csr[beg1 + j];
                ushort8v u = *(const ushort8v*)(xfeat + (size_t)c * 512 + lane * 8);
#pragma unroll
                for (int t = 0; t < 8; t++) a1[t] += b2f(u[t]);
            }
        }
        float d0 = 1.f / fmaxf((float)n0, 1.f);
        float d1 = 1.f / fmaxf((float)n1, 1.f);
        float* dst0 = xl + ((2 * w) * 8 + (lane >> 3)) * 65 + (lane & 7) * 8;
        float* dst1 = xl + ((2 * w + 1) * 8 + (lane >> 3)) * 65 + (lane & 7) * 8;
#pragma unroll
        for (int t = 0; t < 8; t++) dst0[t] = a0[t] * d0;
#pragma unroll
        for (int t = 0; t < 8; t++) dst1[t] = a1[t] * d1;
    }
    __syncthreads();

    // ---- phase 1: GEMM1  h = relu(x @ W1 + b1)
    float h[32];
    {
        const float* bp = b1 + w * 32;
#pragma unroll
        for (int j = 0; j < 32; j++) h[j] = bp[j];
    }
    const float* xrow = xl + lane * 65;
#pragma unroll 8
    for (int k = 0; k < 64; k++) {
        float xv = xrow[k];
        const float* wk = W1 + k * 128 + w * 32;   // uniform -> s_load
#pragma unroll
        for (int j = 0; j < 32; j++) h[j] = fmaf(xv, wk[j], h[j]);
    }
#pragma unroll
    for (int j = 0; j < 32; j++) h[j] = fmaxf(h[j], 0.f);

    // GEMM2 partial: this wave's 32 hidden rows of W2/Wdv
    float acc2[35];
#pragma unroll
    for (int j = 0; j < 35; j++) acc2[j] = 0.f;
    const float* w2p = W2 + (size_t)(w * 32) * 32;
    const float* wdp = Wdv + (size_t)(w * 32) * 3;
#pragma unroll 4
    for (int kc = 0; kc < 32; kc++) {
        float hv = h[kc];
#pragma unroll
        for (int j = 0; j < 32; j++)
            acc2[j] = fmaf(hv, w2p[kc * 32 + j], acc2[j]);
        acc2[32] = fmaf(hv, wdp[kc * 3 + 0], acc2[32]);
        acc2[33] = fmaf(hv, wdp[kc * 3 + 1], acc2[33]);
        acc2[34] = fmaf(hv, wdp[kc * 3 + 2], acc2[34]);
    }
    __syncthreads();   // xl reads done -> smem becomes part2

    // ---- phase 2: 2-phase cross-wave reduction
    if (w >= 2) {
        float* pp = part2 + ((size_t)(w - 2) * 64 + lane) * 37;
#pragma unroll
        for (int j = 0; j < 35; j++) pp[j] = acc2[j];
    }
    __syncthreads();
    if (w < 2) {
        const float* pp = part2 + ((size_t)w * 64 + lane) * 37;
#pragma unroll
        for (int j = 0; j < 35; j++) acc2[j] += pp[j];
    }
    __syncthreads();   // WAR before wave 1 overwrites
    if (w == 1) {
        float* pp = part2 + (size_t)lane * 37;
#pragma unroll
        for (int j = 0; j < 35; j++) pp[j] = acc2[j];
    }
    __syncthreads();
    if (w == 0) {
        const float* pp = part2 + (size_t)lane * 37;
#pragma unroll
        for (int j = 0; j < 35; j++) acc2[j] += pp[j];
        int row = vbase * 8 + lane;     // = v*8+b, vertex-major
        uint_t pk[16];
#pragma unroll
        for (int j = 0; j < 16; j++)
            pk[j] = (uint_t)f2b(acc2[2 * j]) | ((uint_t)f2b(acc2[2 * j + 1]) << 16);
        uint4* yp = (uint4*)(y2 + (size_t)row * 32);
#pragma unroll
        for (int j = 0; j < 4; j++)
            yp[j] = make_uint4(pk[4 * j], pk[4 * j + 1], pk[4 * j + 2], pk[4 * j + 3]);
        float e0 = acc2[32], e1 = acc2[33], e2 = acc2[34];
        int v = row >> 3, b = row & 7;
        const float* vp = verts + ((size_t)b * NV + v) * 3;
        float* orow = out + ((size_t)b * NV + v) * 38;
        orow[32] = (vp[0] + e0) * 1000.f;
        orow[33] = (vp[1] + e1) * 1000.f;
        orow[34] = (vp[2] + e2) * 1000.f;
        orow[35] = e0 * 1000.f;
        orow[36] = e1 * 1000.f;
        orow[37] = e2 * 1000.f;
    }
}

// gather-agg over y2 (256 bf16 = 512 B per vertex-row); write out[0..31]
__global__ void k_agg2(const int* __restrict__ counts, const int* __restrict__ offs,
                       const int* __restrict__ csr, const ushort_t* __restrict__ y2,
                       float* __restrict__ out) {
    int wid = (blockIdx.x * 256 + threadIdx.x) >> 6;   // vertex
    int l = threadIdx.x & 63;
    if (wid >= NV) return;
    int beg = offs[wid], n = counts[wid];
    float a[4];
#pragma unroll
    for (int t = 0; t < 4; t++) a[t] = 0.f;
    for (int j = 0; j < n; j++) {
        int c = csr[beg + j];
        ushort4v u = *(const ushort4v*)(y2 + (size_t)c * 256 + l * 4);
#pragma unroll
        for (int t = 0; t < 4; t++) a[t] += b2f(u[t]);
    }
    float dinv = 1.f / fmaxf((float)n, 1.f);
    int b = l >> 3, o = (l & 7) * 4;
    float* orow = out + ((size_t)b * NV + wid) * 38 + o;
    orow[0] = a[0] * dinv;
    orow[1] = a[1] * dinv;
    orow[2] = a[2] * dinv;
    orow[3] = a[3] * dinv;
}

extern "C" void kernel_launch(void* const* d_in, const int* in_sizes, int n_in,
                              void* d_out, int out_size, void* d_ws, size_t ws_size,
                              hipStream_t stream) {
    const float* fm  = (const float*)d_in[0];
    const float* dm  = (const float*)d_in[1];
    const float* vt  = (const float*)d_in[2];
    const float* fz  = (const float*)d_in[3];
    const float* cz  = (const float*)d_in[4];
    const float* cw  = (const float*)d_in[5];
    const float* cb  = (const float*)d_in[6];
    const float* W1  = (const float*)d_in[7];
    const float* b1  = (const float*)d_in[8];
    const float* W2  = (const float*)d_in[9];
    const float* Wdv = (const float*)d_in[10];
    const int* erow  = (const int*)d_in[11];
    const int* ecol  = (const int*)d_in[12];
    float* out = (float*)d_out;

    float* ws    = (float*)d_ws;
    float* cwT   = ws;                            // 24576 f
    ushort_t* pf = (ushort_t*)(cwT + 24576);      // 2097152 bf16 (1048576 f)
    ushort_t* xfeat = (ushort_t*)((float*)pf + 1048576);   // 6291456 bf16
    ushort_t* y2 = (ushort_t*)((float*)xfeat + 3145728);   // 3145728 bf16
    int* counts  = (int*)((float*)y2 + 1572864);  // 12288
    int* offs    = counts + 12288;
    int* cursor  = offs + 12288;
    int* csr     = cursor + 12288;                // 147456

    hipMemsetAsync(counts, 0, 12288 * sizeof(int), stream);
    hipMemsetAsync(cursor, 0, 12288 * sizeof(int), stream);

    kL1<<<336, 512, 0, stream>>>(cw, cwT, erow, counts);
    kL2<<<513, 512, 0, stream>>>(fm, cwT, pf, counts, offs);
    kL3<<<3360, 512, 0, stream>>>(erow, ecol, offs, cursor, csr,
                                  dm, pf, vt, fz, cz, cb, xfeat);
    k_gmlp<<<1536, 256, 0, stream>>>(counts, offs, csr, xfeat,
                                     W1, b1, W2, Wdv, vt, y2, out);
    k_agg2<<<3072, 256, 0, stream>>>(counts, offs, csr, y2, out);
}